// Round 9
// baseline (2125.792 us; speedup 1.0000x reference)
//
#include <hip/hip_runtime.h>
#include <stdint.h>

// Problem constants
#define BB   64
#define TT   512
#define HT   256
#define OO   128
#define GATES 1024   // 4*H

// ---------------------------------------------------------------------------
// R18 recurrence: R17 4-CU row-split, poll path de-serialized.
// R17 measured step 3440cy (sync ~2800).  Diagnosis: the Ag prefetch was
// issued right BEFORE the poll loop, and scload's s_waitcnt vmcnt(0) drains
// it -> every step pays Ag HBM latency (~900cy) + poll RTT serially.
// R18 moves the Ag prefetch AFTER the first barrier (issued with the dot
// phase; consumer is agsh one step later -> >1500cy slack).  First poll now
// waits only on its own L3 RTT.  Everything else identical to R17 (passed 2x).
// Layout per layer (32768 uint4): idx = (q*16+u)*512 + t;
//   t: s=t>>8 (k-half), G=(t>>6)&3 (gate), rr=t&63;
//   row = 256*G + 64*q + rr;  k = 128*s + 8*u   (u=0..15)

typedef _Float16 half_t;
typedef _Float16 half2_t __attribute__((ext_vector_type(2)));
typedef _Float16 f16x8  __attribute__((ext_vector_type(8)));
typedef float    f32x4  __attribute__((ext_vector_type(4)));

__device__ __forceinline__ half2_t h2_(unsigned int x) {
    return __builtin_bit_cast(half2_t, x);
}
// lgkm-only workgroup barrier: no vmcnt drain per step.
#define WG_BARRIER() do { __builtin_amdgcn_s_waitcnt(0xC07F); \
                          __builtin_amdgcn_s_barrier(); } while (0)

__device__ __forceinline__ float fast_sig(float x) {
    return __builtin_amdgcn_rcpf(1.0f + __expf(-x));
}
__device__ __forceinline__ float fast_tanh(float x) {
    float t = __expf(2.0f * x);
    return 1.0f - 2.0f * __builtin_amdgcn_rcpf(t + 1.0f);
}

// 8-element fp16 dot: acc += w . h  (w, h as uint4 of packed half2)
__device__ __forceinline__ float dot8(float acc, uint4 wv, uint4 h4) {
    acc = __builtin_amdgcn_fdot2(h2_(wv.x), h2_(h4.x), acc, false);
    acc = __builtin_amdgcn_fdot2(h2_(wv.y), h2_(h4.y), acc, false);
    acc = __builtin_amdgcn_fdot2(h2_(wv.z), h2_(h4.z), acc, false);
    acc = __builtin_amdgcn_fdot2(h2_(wv.w), h2_(h4.w), acc, false);
    return acc;
}

// system-coherent load (bypasses L1/L2 -> reads the coherence point)
__device__ __forceinline__ unsigned int scload(const unsigned int* p) {
    unsigned long long a = (unsigned long long)p;
    unsigned int w;
    asm volatile("global_load_dword %0, %1, off sc0 sc1\n\ts_waitcnt vmcnt(0)"
                 : "=v"(w) : "v"(a) : "memory");
    return w;
}

// ---------------------------------------------------------------------------
// Embedding gather + decoder_action output
__global__ __launch_bounds__(256) void embed_kernel(
    const int* __restrict__ actions, const float* __restrict__ emb_table,
    float* __restrict__ X, float* __restrict__ dact)
{
    int row = blockIdx.x;
    int t = row & (TT - 1);
    int id = (t == 0) ? 0 : actions[row - 1];
    X[(int64_t)row * HT + threadIdx.x] = emb_table[(int64_t)id * HT + threadIdx.x];
    if (threadIdx.x == 0) dact[row] = (float)actions[row];
}

// ---------------------------------------------------------------------------
// Repack Whh to the R18 layout; zero the h-exchange buffers (HX) so stale
// stamps from a previous graph replay can never validate.
__global__ __launch_bounds__(256) void repack_whh_mfma_kernel(
    const float* __restrict__ Whh, uint4* __restrict__ Wpkh,
    unsigned int* __restrict__ HXall)
{
    int idx = blockIdx.x * 256 + threadIdx.x;   // 0..65535
    HXall[idx] = 0u;                             // 2 layers x 64b x 4q x 2par x 64

    int g = idx & 32767;
    int l = idx >> 15;
    int t = g & 511;
    int u = (g >> 9) & 15;
    int q = g >> 13;                             // 0..3
    int s = t >> 8, G = (t >> 6) & 3, rr = t & 63;
    int row = 256 * G + 64 * q + rr;
    int k   = 128 * s + 8 * u;

    const float* src = Whh + (int64_t)l * (GATES * HT) + (int64_t)row * HT + k;
    const float4 a = *(const float4*)(src);
    const float4 b = *(const float4*)(src + 4);
    half2_t p0 = {(half_t)a.x, (half_t)a.y};
    half2_t p1 = {(half_t)a.z, (half_t)a.w};
    half2_t p2 = {(half_t)b.x, (half_t)b.y};
    half2_t p3 = {(half_t)b.z, (half_t)b.w};
    uint4 o;
    o.x = __builtin_bit_cast(unsigned int, p0);
    o.y = __builtin_bit_cast(unsigned int, p1);
    o.z = __builtin_bit_cast(unsigned int, p2);
    o.w = __builtin_bit_cast(unsigned int, p3);
    Wpkh[idx] = o;
}

// ---------------------------------------------------------------------------
// MFMA fp16 GEMM: C = act( A @ op(B) + bias1 + bias2 ), fp32 in/out.
template<bool TRANS_B, int ACT>
__global__ __launch_bounds__(256) void mfma_gemm_kernel(
    const float* __restrict__ A, const float* __restrict__ Bm,
    float* __restrict__ C,
    int K, int lda, int ldb, int ldc,
    int64_t sA, int64_t sB, int64_t sC,
    const float* __restrict__ bias1, const float* __restrict__ bias2)
{
    constexpr int BM = 128, BN = 128, BK = 32;
    constexpr int LDT = BK + 8;                  // 40 halfs = 80 B row stride
    __shared__ __align__(16) half_t Asl[BM * LDT];   // 10 KB
    __shared__ __align__(16) half_t Bsl[BN * LDT];   // 10 KB

    const int tid  = threadIdx.x;
    const int wave = tid >> 6;
    const int lane = tid & 63;
    const int wm = (wave & 1) * 64;
    const int wn = (wave >> 1) * 64;
    const int m0 = blockIdx.y * BM;
    const int n0 = blockIdx.x * BN;
    A  += (int64_t)blockIdx.z * sA;
    Bm += (int64_t)blockIdx.z * sB;
    C  += (int64_t)blockIdx.z * sC;

    const int fm = lane & 15;
    const int qd = lane >> 4;

    f32x4 acc[4][4] = {};

    for (int k0 = 0; k0 < K; k0 += BK) {
        #pragma unroll
        for (int i = 0; i < 4; i++) {
            int idx = tid + i * 256;             // 0..1023
            int r  = idx >> 3;                   // 0..127
            int kq = idx & 7;                    // 0..7
            float4 v = *(const float4*)(A + (int64_t)(m0 + r) * lda + k0 + kq * 4);
            half_t* d = &Asl[r * LDT + kq * 4];
            d[0] = (half_t)v.x; d[1] = (half_t)v.y;
            d[2] = (half_t)v.z; d[3] = (half_t)v.w;
        }
        if (TRANS_B) {
            #pragma unroll
            for (int i = 0; i < 4; i++) {
                int idx = tid + i * 256;
                int r  = idx >> 3;
                int kq = idx & 7;
                float4 v = *(const float4*)(Bm + (int64_t)(n0 + r) * ldb + k0 + kq * 4);
                half_t* d = &Bsl[r * LDT + kq * 4];
                d[0] = (half_t)v.x; d[1] = (half_t)v.y;
                d[2] = (half_t)v.z; d[3] = (half_t)v.w;
            }
        } else {
            #pragma unroll
            for (int i = 0; i < 4; i++) {
                int idx = tid + i * 256;
                int kk = idx >> 5;               // 0..31
                int nq = idx & 31;               // 0..31 (x4 n)
                float4 v = *(const float4*)(Bm + (int64_t)(k0 + kk) * ldb + n0 + nq * 4);
                Bsl[(nq * 4 + 0) * LDT + kk] = (half_t)v.x;
                Bsl[(nq * 4 + 1) * LDT + kk] = (half_t)v.y;
                Bsl[(nq * 4 + 2) * LDT + kk] = (half_t)v.z;
                Bsl[(nq * 4 + 3) * LDT + kk] = (half_t)v.w;
            }
        }
        __syncthreads();

        f16x8 af[4], bf[4];
        #pragma unroll
        for (int t = 0; t < 4; t++)
            af[t] = *(const f16x8*)&Asl[(wm + t * 16 + fm) * LDT + qd * 8];
        #pragma unroll
        for (int t = 0; t < 4; t++)
            bf[t] = *(const f16x8*)&Bsl[(wn + t * 16 + fm) * LDT + qd * 8];
        #pragma unroll
        for (int mt = 0; mt < 4; mt++)
            #pragma unroll
            for (int nt = 0; nt < 4; nt++)
                acc[mt][nt] = __builtin_amdgcn_mfma_f32_16x16x32_f16(
                                  af[mt], bf[nt], acc[mt][nt], 0, 0, 0);
        __syncthreads();
    }

    #pragma unroll
    for (int nt = 0; nt < 4; nt++) {
        int n = n0 + wn + nt * 16 + fm;
        float bv = 0.0f;
        if (bias1) bv += bias1[n];
        if (bias2) bv += bias2[n];
        #pragma unroll
        for (int mt = 0; mt < 4; mt++) {
            #pragma unroll
            for (int r = 0; r < 4; r++) {
                int m = m0 + wm + mt * 16 + qd * 4 + r;
                float v = acc[mt][nt][r] + bv;
                if (ACT == 1) v = tanhf(v);
                C[(int64_t)m * ldc + n] = v;
            }
        }
    }
}

// ---------------------------------------------------------------------------
// Generic fp32 tiled GEMM (kept for attention + output chain precision).
template<bool TRANS_B, int ACT>
__global__ __launch_bounds__(256) void gemm128_kernel(
    const float* __restrict__ A, const float* __restrict__ Bm,
    float* __restrict__ C,
    int K, int lda, int ldb, int ldc,
    int64_t sA, int64_t sB, int64_t sC,
    const float* __restrict__ bias1, const float* __restrict__ bias2)
{
    constexpr int BM = 128, BN = 128, BK = 16;
    __shared__ __align__(16) float As[BK][BM + 4];
    __shared__ __align__(16) float Bs[BK][BN + 4];

    const int tid = threadIdx.x;
    const int m0 = blockIdx.y * BM;
    const int n0 = blockIdx.x * BN;
    A  += (int64_t)blockIdx.z * sA;
    Bm += (int64_t)blockIdx.z * sB;
    C  += (int64_t)blockIdx.z * sC;

    const int tm = tid & 15;
    const int tn = tid >> 4;

    float acc[8][8] = {};

    for (int k0 = 0; k0 < K; k0 += BK) {
        #pragma unroll
        for (int i = 0; i < 2; i++) {
            int idx = tid + i * 256;
            int ar = idx >> 2;
            int ak = (idx & 3) * 4;
            const float4 v = *(const float4*)(A + (int64_t)(m0 + ar) * lda + k0 + ak);
            As[ak + 0][ar] = v.x; As[ak + 1][ar] = v.y;
            As[ak + 2][ar] = v.z; As[ak + 3][ar] = v.w;
        }
        if (TRANS_B) {
            #pragma unroll
            for (int i = 0; i < 2; i++) {
                int idx = tid + i * 256;
                int br = idx >> 2;
                int bk = (idx & 3) * 4;
                const float4 v = *(const float4*)(Bm + (int64_t)(n0 + br) * ldb + k0 + bk);
                Bs[bk + 0][br] = v.x; Bs[bk + 1][br] = v.y;
                Bs[bk + 2][br] = v.z; Bs[bk + 3][br] = v.w;
            }
        } else {
            #pragma unroll
            for (int i = 0; i < 2; i++) {
                int idx = tid + i * 256;
                int bk = idx >> 5;
                int bn = (idx & 31) * 4;
                const float4 v = *(const float4*)(Bm + (int64_t)(k0 + bk) * ldb + n0 + bn);
                *(float4*)&Bs[bk][bn] = v;
            }
        }
        __syncthreads();

        #pragma unroll
        for (int k = 0; k < BK; k++) {
            float a[8], b[8];
            *(float4*)&a[0] = *(const float4*)&As[k][tm * 8];
            *(float4*)&a[4] = *(const float4*)&As[k][tm * 8 + 4];
            *(float4*)&b[0] = *(const float4*)&Bs[k][tn * 8];
            *(float4*)&b[4] = *(const float4*)&Bs[k][tn * 8 + 4];
            #pragma unroll
            for (int i = 0; i < 8; i++)
                #pragma unroll
                for (int j = 0; j < 8; j++)
                    acc[i][j] += a[i] * b[j];
        }
        __syncthreads();
    }

    float bv[8];
    #pragma unroll
    for (int j = 0; j < 8; j++) {
        int n = n0 + tn * 8 + j;
        float b = 0.0f;
        if (bias1) b += bias1[n];
        if (bias2) b += bias2[n];
        bv[j] = b;
    }
    #pragma unroll
    for (int i = 0; i < 8; i++) {
        int64_t m = m0 + tm * 8 + i;
        float o[8];
        #pragma unroll
        for (int j = 0; j < 8; j++) {
            float v = acc[i][j] + bv[j];
            if (ACT == 1) v = tanhf(v);
            o[j] = v;
        }
        *(float4*)(C + m * ldc + n0 + tn * 8)     = make_float4(o[0], o[1], o[2], o[3]);
        *(float4*)(C + m * ldc + n0 + tn * 8 + 4) = make_float4(o[4], o[5], o[6], o[7]);
    }
}

// ---------------------------------------------------------------------------
// LSTM recurrence (R18: 4-CU split, sc-load sync, Ag off the poll path).
// grid = 256 blocks (b = blk>>2, q = blk&3), 512 threads; grid <= CU count
// -> all co-resident.
__global__ __launch_bounds__(512)
__attribute__((amdgpu_waves_per_eu(2, 2)))
void lstm_rec_kernel(
    const float* __restrict__ Ag,
    const uint4* __restrict__ Wpk,
    const float* __restrict__ h0l,
    const float* __restrict__ c0l,
    float* __restrict__ X, int ldx,
    unsigned int* __restrict__ HX)
{
    const int bq  = blockIdx.x;
    const int b   = bq >> 2;
    const int q   = bq & 3;
    const int tid = threadIdx.x;
    const int s   = tid >> 8;        // k-half

    __shared__ __align__(16) float          part[512];   // 2 KB
    __shared__ __align__(16) float          agsh[256];   // 1 KB (input-gate bias)
    __shared__ __align__(16) unsigned short hsh[HT];     // 512 B

    // weights: 16 uint4 = 64 arch VGPRs, fully resident
    uint4 wv[16];
    {
        const uint4* Wq = Wpk + (q * 16) * 512 + tid;
        #pragma unroll
        for (int u = 0; u < 16; u++) wv[u] = Wq[u * 512];
    }

    // init full h in LDS; own-quarter c in regs (threads 0..63)
    if (tid < HT) {
        half_t hv = (half_t)h0l[b * HT + tid];
        hsh[tid] = __builtin_bit_cast(unsigned short, hv);
    }
    float c = 0.0f;
    if (tid < 64) c = c0l[b * HT + 64 * q + tid];

    // Ag base for this thread's gate row (threads 0..255 use it)
    const float* AgB = Ag + (int64_t)b * TT * GATES
                     + (256 * ((tid >> 6) & 3) + 64 * q + (tid & 63));
    unsigned int* HXb = HX + b * 512;   // 4q x 2par x 64 words

    // partner-fetch assignment: waves 1..3, one wave per partner quarter
    int wq = 0, wi = 0;
    if (tid >= 64 && tid < 256) {
        int i = tid - 64;
        int p = i >> 6;
        wq = p + (p >= q ? 1 : 0);
        wi = i & 63;
    }

    const uint4* hp4 = (const uint4*)hsh;
    float agc = 0.0f;
    if (tid < 256) agc = AgB[0];
    __syncthreads();

    #pragma unroll 1
    for (int st = 0; st < TT; st++) {
        // fetch partner h-quarters (version st): stamp-validated words,
        // plain sc0/sc1 loads; NO other vmem in flight -> first poll is one
        // clean L3 RTT (Ag prefetch moved below the barrier, R18 fix).
        if (st > 0 && tid >= 64 && tid < 256) {
            unsigned int* src = HXb + wq * 128 + (st & 1) * 64 + wi;
            unsigned int w = scload(src);
            int tries = 0;
            while ((w >> 16) != (unsigned)st) {
                if (++tries > 4096) {
                    w = atomicOr(src, 0u);
                    tries = 0;
                } else {
                    w = scload(src);
                }
            }
            hsh[64 * wq + wi] = (unsigned short)(w & 0xffffu);
        }
        WG_BARRIER();                            // hsh complete

        // prefetch next step's Ag (consumed via agsh one step later; has
        // dot+tail+next-poll >1500cy of slack to complete)
        float agn = 0.0f;
        {
            int stn = (st + 1 < TT) ? st + 1 : st;
            if (tid < 256) agn = AgB[(int64_t)stn * GATES];
        }

        // dot: own row, own k-half (h chunks are wave-uniform LDS broadcasts)
        float a = 0.0f;
        #pragma unroll
        for (int u = 0; u < 16; u++)
            a = dot8(a, wv[u], hp4[16 * s + u]);
        part[tid] = a;
        if (tid < 256) agsh[tid] = agc;
        WG_BARRIER();

        // tail: combine + gates + publish FIRST, then X store + hsh
        if (tid < 64) {
            float gi = part[tid]       + part[256 + tid]       + agsh[tid];
            float gf = part[64 + tid]  + part[320 + tid]       + agsh[64 + tid];
            float gg = part[128 + tid] + part[384 + tid]       + agsh[128 + tid];
            float go = part[192 + tid] + part[448 + tid]       + agsh[192 + tid];
            c = fast_sig(gf) * c + fast_sig(gi) * fast_tanh(gg);
            float h = fast_sig(go) * fast_tanh(c);
            half_t hh = (half_t)h;
            unsigned short hb = __builtin_bit_cast(unsigned short, hh);
            if (st + 1 < TT) {
                unsigned int word = ((unsigned)(st + 1) << 16) | (unsigned)hb;
                atomicExch(HXb + q * 128 + ((st + 1) & 1) * 64 + tid, word);
            }
            X[((int64_t)b * TT + st) * ldx + 64 * q + tid] = h;
            hsh[64 * q + tid] = hb;
        }
        agc = agn;
        // no trailing barrier: next iteration's WG_BARRIER (post-fetch) orders
        // the tail's hsh/part accesses against the next dot phase.
    }
}

// ---------------------------------------------------------------------------
__global__ __launch_bounds__(256) void softmax512_kernel(float* __restrict__ S)
{
    int row = blockIdx.x * 4 + (threadIdx.x >> 6);
    int lane = threadIdx.x & 63;
    float* p = S + (int64_t)row * 512 + lane * 8;
    float4 v0 = *(float4*)p;
    float4 v1 = *(float4*)(p + 4);
    float m = fmaxf(fmaxf(fmaxf(v0.x, v0.y), fmaxf(v0.z, v0.w)),
                    fmaxf(fmaxf(v1.x, v1.y), fmaxf(v1.z, v1.w)));
    #pragma unroll
    for (int off = 32; off; off >>= 1) m = fmaxf(m, __shfl_xor(m, off));
    v0.x = __expf(v0.x - m); v0.y = __expf(v0.y - m);
    v0.z = __expf(v0.z - m); v0.w = __expf(v0.w - m);
    v1.x = __expf(v1.x - m); v1.y = __expf(v1.y - m);
    v1.z = __expf(v1.z - m); v1.w = __expf(v1.w - m);
    float s = v0.x + v0.y + v0.z + v0.w + v1.x + v1.y + v1.z + v1.w;
    #pragma unroll
    for (int off = 32; off; off >>= 1) s += __shfl_xor(s, off);
    float inv = 1.0f / s;
    v0.x *= inv; v0.y *= inv; v0.z *= inv; v0.w *= inv;
    v1.x *= inv; v1.y *= inv; v1.z *= inv; v1.w *= inv;
    *(float4*)p = v0;
    *(float4*)(p + 4) = v1;
}

__global__ __launch_bounds__(256) void values_kernel(
    const float* __restrict__ Q, const float* __restrict__ L, float* __restrict__ V)
{
    int row = blockIdx.x * 4 + (threadIdx.x >> 6);
    int lane = threadIdx.x & 63;
    float2 q = *(const float2*)(Q + (int64_t)row * OO + lane * 2);
    float2 l = *(const float2*)(L + (int64_t)row * OO + lane * 2);
    float s = q.x * l.x + q.y * l.y;
    #pragma unroll
    for (int off = 32; off; off >>= 1) s += __shfl_xor(s, off);
    if (lane == 0) V[row] = s;
}

// ---------------------------------------------------------------------------
extern "C" void kernel_launch(void* const* d_in, const int* in_sizes, int n_in,
                              void* d_out, int out_size, void* d_ws, size_t ws_size,
                              hipStream_t stream)
{
    const float* enc      = (const float*)d_in[0];
    const float* h0       = (const float*)d_in[1];
    const float* c0       = (const float*)d_in[2];
    const int*   actions  = (const int*)  d_in[3];
    const float* emb_t    = (const float*)d_in[4];
    const float* Wih      = (const float*)d_in[5];
    const float* Whh      = (const float*)d_in[6];
    const float* bih      = (const float*)d_in[7];
    const float* bhh      = (const float*)d_in[8];
    const float* W_attn   = (const float*)d_in[9];
    const float* b_attn   = (const float*)d_in[10];
    const float* W_concat = (const float*)d_in[11];
    const float* b_concat = (const float*)d_in[12];
    const float* W_out    = (const float*)d_in[13];
    const float* W_critic = (const float*)d_in[14];
    const float* b_critic = (const float*)d_in[15];
    (void)in_sizes; (void)n_in; (void)out_size; (void)ws_size;

    const int M = BB * TT;                 // 32768

    float* out    = (float*)d_out;
    float* dact   = out;
    float* logits = out + M;
    float* values = out + M + (int64_t)M * OO;

    float* ws    = (float*)d_ws;
    float* gates = ws;
    float* xbuf  = ws + 33554432;
    float* cat   = ws + 41943040;
    float* keysR = ws + 58720256;
    float* keys  = keysR;
    uint4* Wpkh  = (uint4*)keysR;          // 1 MB; dead before keys written
    unsigned int* HX0 = (unsigned int*)(ws + 59000000);  // 128 KB, dead before keys
    unsigned int* HX1 = HX0 + 32768;
    float* scores = gates;
    float* qv     = gates;
    float* dec    = xbuf;

    const int64_t LWP = 32768;             // uint4s per layer in Wpkh
    const int64_t LW  = (int64_t)GATES * HT;

    // 1) embedding + decoder_action
    hipLaunchKernelGGL(embed_kernel, dim3(M), dim3(256), 0, stream,
                       actions, emb_t, xbuf, dact);
    // 2) repack Whh + zero h-exchange buffers
    hipLaunchKernelGGL(repack_whh_mfma_kernel, dim3(256), dim3(256), 0, stream,
                       Whh, Wpkh, HX0);
    // 3) layer-0 input GEMM (MFMA fp16): gates = emb @ Wih0^T + bih0 + bhh0
    hipLaunchKernelGGL((mfma_gemm_kernel<true, 0>), dim3(8, 256, 1), dim3(256), 0, stream,
                       xbuf, Wih, gates, HT, HT, HT, GATES,
                       (int64_t)0, (int64_t)0, (int64_t)0, bih, bhh);
    // 4) layer-0 recurrence -> X1 (xbuf, ldx=256)
    hipLaunchKernelGGL(lstm_rec_kernel, dim3(BB * 4), dim3(512), 0, stream,
                       gates, Wpkh, h0, c0, xbuf, HT, HX0);
    // 5) layer-1 input GEMM (MFMA fp16)
    hipLaunchKernelGGL((mfma_gemm_kernel<true, 0>), dim3(8, 256, 1), dim3(256), 0, stream,
                       xbuf, Wih + LW, gates, HT, HT, HT, GATES,
                       (int64_t)0, (int64_t)0, (int64_t)0, bih + GATES, bhh + GATES);
    // 6) layer-1 recurrence -> cat[:, 0:256] (ldx=512)
    hipLaunchKernelGGL(lstm_rec_kernel, dim3(BB * 4), dim3(512), 0, stream,
                       gates, Wpkh + LWP, h0 + BB * HT, c0 + BB * HT, cat, 2 * HT, HX1);
    // 7) keys = enc @ W_attn^T + b_attn (MFMA fp16; overwrites Wpkh/HX region)
    hipLaunchKernelGGL((mfma_gemm_kernel<true, 0>), dim3(2, 256, 1), dim3(256), 0, stream,
                       enc, W_attn, keys, HT, HT, HT, HT,
                       (int64_t)0, (int64_t)0, (int64_t)0, b_attn, (const float*)nullptr);
    // 8) scores[b] = out[b] @ keys[b]^T  (fp32, precision-sensitive softmax input)
    hipLaunchKernelGGL((gemm128_kernel<true, 0>), dim3(4, 4, BB), dim3(256), 0, stream,
                       cat, keys, scores, HT, 2 * HT, HT, TT,
                       (int64_t)TT * 2 * HT, (int64_t)TT * HT, (int64_t)TT * TT,
                       (const float*)nullptr, (const float*)nullptr);
    // 9) softmax
    hipLaunchKernelGGL(softmax512_kernel, dim3(M / 4), dim3(256), 0, stream, scores);
    // 10) ctx[b] = P[b] @ enc[b] -> cat[:,256:]  (fp32)
    hipLaunchKernelGGL((gemm128_kernel<false, 0>), dim3(2, 4, BB), dim3(256), 0, stream,
                       scores, enc, cat + HT, TT, TT, HT, 2 * HT,
                       (int64_t)TT * TT, (int64_t)TT * HT, (int64_t)TT * 2 * HT,
                       (const float*)nullptr, (const float*)nullptr);
    // 11) dec = tanh(cat @ W_concat^T + b_concat) (MFMA fp16)
    hipLaunchKernelGGL((mfma_gemm_kernel<true, 1>), dim3(2, 256, 1), dim3(256), 0, stream,
                       cat, W_concat, dec, 2 * HT, 2 * HT, 2 * HT, HT,
                       (int64_t)0, (int64_t)0, (int64_t)0, b_concat, (const float*)nullptr);
    // 12) logits = dec @ W_out^T  (fp32 — output path)
    hipLaunchKernelGGL((gemm128_kernel<true, 0>), dim3(1, 256, 1), dim3(256), 0, stream,
                       dec, W_out, logits, HT, HT, HT, OO,
                       (int64_t)0, (int64_t)0, (int64_t)0,
                       (const float*)nullptr, (const float*)nullptr);
    // 13) qv = logits @ W_critic^T + b_critic  (fp32 — output path)
    hipLaunchKernelGGL((gemm128_kernel<true, 0>), dim3(1, 256, 1), dim3(256), 0, stream,
                       logits, W_critic, qv, OO, OO, OO, OO,
                       (int64_t)0, (int64_t)0, (int64_t)0, b_critic, (const float*)nullptr);
    // 14) values
    hipLaunchKernelGGL(values_kernel, dim3(M / 4), dim3(256), 0, stream,
                       qv, logits, values);
}

// Round 10
// 1924.191 us; speedup vs baseline: 1.1048x; 1.1048x over previous
//
#include <hip/hip_runtime.h>
#include <stdint.h>

// Problem constants
#define BB   64
#define TT   512
#define HT   256
#define OO   128
#define GATES 1024   // 4*H

// R19: fused two-layer pipelined recurrence.
// Serial per-layer floor is proven (~740us x2: R10 delivery-bound, R15/17/18
// sync-bound).  Layers are pipelined instead: 192 co-resident blocks,
// one-directional dataflow A(L0 rec) -> B(L1 input matvec) -> C(L1 rec).
// A publishes h0_t stamped (write-once flat buffer = no reuse hazards);
// B polls h0, computes Wih1@h0+biases, publishes Ag1 (16-deep ring,
// release-stamp, counter back-pressure); C consumes Ag1 with 1-step
// prefetch slack, h1 fully CU-local.  Each role = R10's proven 512-thread
// weight-persistent fdot2 structure (10/4/2 reg/LDS/stream pairs).
#define PREG 10
#define PLDS 4
#define PSTR 2
#define UREG (2*PREG)
#define ULDS (2*PLDS)
#define AGDEPTH 16

typedef _Float16 half_t;
typedef _Float16 half2_t __attribute__((ext_vector_type(2)));
typedef float    f32x4  __attribute__((ext_vector_type(4)));

__device__ __forceinline__ half2_t h2_(unsigned int x) {
    return __builtin_bit_cast(half2_t, x);
}
#define WG_BARRIER() do { __builtin_amdgcn_s_waitcnt(0xC07F); \
                          __builtin_amdgcn_s_barrier(); } while (0)

__device__ __forceinline__ float fast_sig(float x) {
    return __builtin_amdgcn_rcpf(1.0f + __expf(-x));
}
__device__ __forceinline__ float fast_tanh(float x) {
    float t = __expf(2.0f * x);
    return 1.0f - 2.0f * __builtin_amdgcn_rcpf(t + 1.0f);
}

// system-coherent accesses (read/write the coherence point; proven R17/R18)
__device__ __forceinline__ unsigned int scload(const unsigned int* p) {
    unsigned long long a = (unsigned long long)p;
    unsigned int w;
    asm volatile("global_load_dword %0, %1, off sc0 sc1\n\ts_waitcnt vmcnt(0)"
                 : "=v"(w) : "v"(a) : "memory");
    return w;
}
__device__ __forceinline__ f32x4 scload4(const float* p) {
    unsigned long long a = (unsigned long long)p;
    f32x4 v;
    asm volatile("global_load_dwordx4 %0, %1, off sc0 sc1\n\ts_waitcnt vmcnt(0)"
                 : "=v"(v) : "v"(a) : "memory");
    return v;
}
__device__ __forceinline__ void scstore4(float* p, f32x4 v) {
    unsigned long long a = (unsigned long long)p;
    asm volatile("global_store_dwordx4 %0, %1, off sc0 sc1"
                 :: "v"(a), "v"(v) : "memory");
}

#define PAIR_DOT(wa0, wb0, wa1, wb1, h4)                                  \
    do {                                                                   \
        a0 = __builtin_amdgcn_fdot2(h2_((wa0).x), h2_((h4).x), a0, false); \
        a0 = __builtin_amdgcn_fdot2(h2_((wa0).y), h2_((h4).y), a0, false); \
        a1 = __builtin_amdgcn_fdot2(h2_((wa0).z), h2_((h4).x), a1, false); \
        a1 = __builtin_amdgcn_fdot2(h2_((wa0).w), h2_((h4).y), a1, false); \
        a2 = __builtin_amdgcn_fdot2(h2_((wb0).x), h2_((h4).x), a2, false); \
        a2 = __builtin_amdgcn_fdot2(h2_((wb0).y), h2_((h4).y), a2, false); \
        a3 = __builtin_amdgcn_fdot2(h2_((wb0).z), h2_((h4).x), a3, false); \
        a3 = __builtin_amdgcn_fdot2(h2_((wb0).w), h2_((h4).y), a3, false); \
        a0 = __builtin_amdgcn_fdot2(h2_((wa1).x), h2_((h4).z), a0, false); \
        a0 = __builtin_amdgcn_fdot2(h2_((wa1).y), h2_((h4).w), a0, false); \
        a1 = __builtin_amdgcn_fdot2(h2_((wa1).z), h2_((h4).z), a1, false); \
        a1 = __builtin_amdgcn_fdot2(h2_((wa1).w), h2_((h4).w), a1, false); \
        a2 = __builtin_amdgcn_fdot2(h2_((wb1).x), h2_((h4).z), a2, false); \
        a2 = __builtin_amdgcn_fdot2(h2_((wb1).y), h2_((h4).w), a2, false); \
        a3 = __builtin_amdgcn_fdot2(h2_((wb1).z), h2_((h4).z), a3, false); \
        a3 = __builtin_amdgcn_fdot2(h2_((wb1).w), h2_((h4).w), a3, false); \
    } while (0)

// full dot phase over this thread's 4 gate rows x k-half (R10 verbatim)
#define DOT_PHASE()                                                        \
    do {                                                                   \
        _Pragma("unroll 2")                                                \
        for (int p = 0; p < PSTR; p++) {                                   \
            uint4 wa0 = Ws[(p * 4 + 0) * 512 + tid];                       \
            uint4 wb0 = Ws[(p * 4 + 1) * 512 + tid];                       \
            uint4 wa1 = Ws[(p * 4 + 2) * 512 + tid];                       \
            uint4 wb1 = Ws[(p * 4 + 3) * 512 + tid];                       \
            uint4 h4  = hp4[hb + PREG + PLDS + p];                         \
            PAIR_DOT(wa0, wb0, wa1, wb1, h4);                              \
        }                                                                  \
        _Pragma("unroll")                                                  \
        for (int p = 0; p < PLDS; p++) {                                   \
            uint4 wa0 = Wlh[(p * 4 + 0) * 512 + tid];                      \
            uint4 wb0 = Wlh[(p * 4 + 1) * 512 + tid];                      \
            uint4 wa1 = Wlh[(p * 4 + 2) * 512 + tid];                      \
            uint4 wb1 = Wlh[(p * 4 + 3) * 512 + tid];                      \
            uint4 h4  = hp4[hb + PREG + p];                                \
            PAIR_DOT(wa0, wb0, wa1, wb1, h4);                              \
        }                                                                  \
        _Pragma("unroll")                                                  \
        for (int p = 0; p < PREG; p++) {                                   \
            uint4 h4 = hp4[hb + p];                                        \
            PAIR_DOT(wreg[4 * p], wreg[4 * p + 1],                         \
                     wreg[4 * p + 2], wreg[4 * p + 3], h4);                \
        }                                                                  \
    } while (0)

// ---------------------------------------------------------------------------
__global__ __launch_bounds__(256) void embed_kernel(
    const int* __restrict__ actions, const float* __restrict__ emb_table,
    float* __restrict__ X, float* __restrict__ dact)
{
    int row = blockIdx.x;
    int t = row & (TT - 1);
    int id = (t == 0) ? 0 : actions[row - 1];
    X[(int64_t)row * HT + threadIdx.x] = emb_table[(int64_t)id * HT + threadIdx.x];
    if (threadIdx.x == 0) dact[row] = (float)actions[row];
}

// ---------------------------------------------------------------------------
// Repack 3 weight matrices to the R10 fp16 layout:
// slot 0 = Whh layer0 (role A), slot 1 = Whh layer1 (role C),
// slot 2 = Wih layer1 (role B).
__global__ __launch_bounds__(256) void repack_w_kernel(
    const float* __restrict__ Whh, const float* __restrict__ Wih,
    uint4* __restrict__ Wpkh)
{
    int idx = blockIdx.x * 256 + threadIdx.x;   // 0..98303
    int g   = idx & 32767;
    int l   = idx >> 15;                        // 0..2
    int tid = g & 511;
    int ab  = (g >> 9) & 1;
    int u   = (g >> 10) & 31;
    int s = tid >> 8, q = tid & 255;
    int r0 = 4 * q + 2 * ab;
    int k  = 128 * s + 4 * u;
    const float* base = (l == 0) ? Whh
                      : (l == 1) ? Whh + (int64_t)GATES * HT
                                 : Wih + (int64_t)GATES * HT;
    const float4 a = *(const float4*)(base + (int64_t)r0 * HT + k);
    const float4 b = *(const float4*)(base + (int64_t)(r0 + 1) * HT + k);
    half2_t p0 = {(half_t)a.x, (half_t)a.y};
    half2_t p1 = {(half_t)a.z, (half_t)a.w};
    half2_t p2 = {(half_t)b.x, (half_t)b.y};
    half2_t p3 = {(half_t)b.z, (half_t)b.w};
    uint4 o;
    o.x = __builtin_bit_cast(unsigned int, p0);
    o.y = __builtin_bit_cast(unsigned int, p1);
    o.z = __builtin_bit_cast(unsigned int, p2);
    o.w = __builtin_bit_cast(unsigned int, p3);
    Wpkh[idx] = o;
}

// ---------------------------------------------------------------------------
// Zero the h0 exchange buffer (stale floats could alias stamps) + Ag1 ring
// stamps + progress counters.  Runs after GEMM0 consumed emb (same region).
__global__ __launch_bounds__(256) void hxzero_kernel(
    uint4* __restrict__ HX4, unsigned int* __restrict__ AGS,
    unsigned int* __restrict__ CCTR)
{
    int i = blockIdx.x * 256 + threadIdx.x;     // grid 8192 -> 2M uint4
    HX4[i] = make_uint4(0u, 0u, 0u, 0u);
    if (blockIdx.x == 0) {
        for (int k = threadIdx.x; k < 64 * AGDEPTH; k += 256) AGS[k] = 0u;
        if (threadIdx.x < 64) CCTR[threadIdx.x] = 0u;
    }
}

// ---------------------------------------------------------------------------
// MFMA fp16 GEMM: C = act( A @ op(B) + bias1 + bias2 ), fp32 in/out.
template<bool TRANS_B, int ACT>
__global__ __launch_bounds__(256) void mfma_gemm_kernel(
    const float* __restrict__ A, const float* __restrict__ Bm,
    float* __restrict__ C,
    int K, int lda, int ldb, int ldc,
    int64_t sA, int64_t sB, int64_t sC,
    const float* __restrict__ bias1, const float* __restrict__ bias2)
{
    constexpr int BM = 128, BN = 128, BK = 32;
    constexpr int LDT = BK + 8;
    __shared__ __align__(16) half_t Asl[BM * LDT];
    __shared__ __align__(16) half_t Bsl[BN * LDT];

    const int tid  = threadIdx.x;
    const int wave = tid >> 6;
    const int lane = tid & 63;
    const int wm = (wave & 1) * 64;
    const int wn = (wave >> 1) * 64;
    const int m0 = blockIdx.y * BM;
    const int n0 = blockIdx.x * BN;
    A  += (int64_t)blockIdx.z * sA;
    Bm += (int64_t)blockIdx.z * sB;
    C  += (int64_t)blockIdx.z * sC;

    const int fm = lane & 15;
    const int qd = lane >> 4;

    f32x4 acc[4][4] = {};

    for (int k0 = 0; k0 < K; k0 += BK) {
        #pragma unroll
        for (int i = 0; i < 4; i++) {
            int idx = tid + i * 256;
            int r  = idx >> 3;
            int kq = idx & 7;
            float4 v = *(const float4*)(A + (int64_t)(m0 + r) * lda + k0 + kq * 4);
            half_t* d = &Asl[r * LDT + kq * 4];
            d[0] = (half_t)v.x; d[1] = (half_t)v.y;
            d[2] = (half_t)v.z; d[3] = (half_t)v.w;
        }
        if (TRANS_B) {
            #pragma unroll
            for (int i = 0; i < 4; i++) {
                int idx = tid + i * 256;
                int r  = idx >> 3;
                int kq = idx & 7;
                float4 v = *(const float4*)(Bm + (int64_t)(n0 + r) * ldb + k0 + kq * 4);
                half_t* d = &Bsl[r * LDT + kq * 4];
                d[0] = (half_t)v.x; d[1] = (half_t)v.y;
                d[2] = (half_t)v.z; d[3] = (half_t)v.w;
            }
        } else {
            #pragma unroll
            for (int i = 0; i < 4; i++) {
                int idx = tid + i * 256;
                int kk = idx >> 5;
                int nq = idx & 31;
                float4 v = *(const float4*)(Bm + (int64_t)(k0 + kk) * ldb + n0 + nq * 4);
                Bsl[(nq * 4 + 0) * LDT + kk] = (half_t)v.x;
                Bsl[(nq * 4 + 1) * LDT + kk] = (half_t)v.y;
                Bsl[(nq * 4 + 2) * LDT + kk] = (half_t)v.z;
                Bsl[(nq * 4 + 3) * LDT + kk] = (half_t)v.w;
            }
        }
        __syncthreads();

        typedef _Float16 f16x8 __attribute__((ext_vector_type(8)));
        f16x8 af[4], bf[4];
        #pragma unroll
        for (int t = 0; t < 4; t++)
            af[t] = *(const f16x8*)&Asl[(wm + t * 16 + fm) * LDT + qd * 8];
        #pragma unroll
        for (int t = 0; t < 4; t++)
            bf[t] = *(const f16x8*)&Bsl[(wn + t * 16 + fm) * LDT + qd * 8];
        #pragma unroll
        for (int mt = 0; mt < 4; mt++)
            #pragma unroll
            for (int nt = 0; nt < 4; nt++)
                acc[mt][nt] = __builtin_amdgcn_mfma_f32_16x16x32_f16(
                                  af[mt], bf[nt], acc[mt][nt], 0, 0, 0);
        __syncthreads();
    }

    #pragma unroll
    for (int nt = 0; nt < 4; nt++) {
        int n = n0 + wn + nt * 16 + fm;
        float bv = 0.0f;
        if (bias1) bv += bias1[n];
        if (bias2) bv += bias2[n];
        #pragma unroll
        for (int mt = 0; mt < 4; mt++) {
            #pragma unroll
            for (int r = 0; r < 4; r++) {
                int m = m0 + wm + mt * 16 + qd * 4 + r;
                float v = acc[mt][nt][r] + bv;
                if (ACT == 1) v = tanhf(v);
                C[(int64_t)m * ldc + n] = v;
            }
        }
    }
}

// ---------------------------------------------------------------------------
// Generic fp32 tiled GEMM (attention + output chain precision).
template<bool TRANS_B, int ACT>
__global__ __launch_bounds__(256) void gemm128_kernel(
    const float* __restrict__ A, const float* __restrict__ Bm,
    float* __restrict__ C,
    int K, int lda, int ldb, int ldc,
    int64_t sA, int64_t sB, int64_t sC,
    const float* __restrict__ bias1, const float* __restrict__ bias2)
{
    constexpr int BM = 128, BN = 128, BK = 16;
    __shared__ __align__(16) float As[BK][BM + 4];
    __shared__ __align__(16) float Bs[BK][BN + 4];

    const int tid = threadIdx.x;
    const int m0 = blockIdx.y * BM;
    const int n0 = blockIdx.x * BN;
    A  += (int64_t)blockIdx.z * sA;
    Bm += (int64_t)blockIdx.z * sB;
    C  += (int64_t)blockIdx.z * sC;

    const int tm = tid & 15;
    const int tn = tid >> 4;

    float acc[8][8] = {};

    for (int k0 = 0; k0 < K; k0 += BK) {
        #pragma unroll
        for (int i = 0; i < 2; i++) {
            int idx = tid + i * 256;
            int ar = idx >> 2;
            int ak = (idx & 3) * 4;
            const float4 v = *(const float4*)(A + (int64_t)(m0 + ar) * lda + k0 + ak);
            As[ak + 0][ar] = v.x; As[ak + 1][ar] = v.y;
            As[ak + 2][ar] = v.z; As[ak + 3][ar] = v.w;
        }
        if (TRANS_B) {
            #pragma unroll
            for (int i = 0; i < 2; i++) {
                int idx = tid + i * 256;
                int br = idx >> 2;
                int bk = (idx & 3) * 4;
                const float4 v = *(const float4*)(Bm + (int64_t)(n0 + br) * ldb + k0 + bk);
                Bs[bk + 0][br] = v.x; Bs[bk + 1][br] = v.y;
                Bs[bk + 2][br] = v.z; Bs[bk + 3][br] = v.w;
            }
        } else {
            #pragma unroll
            for (int i = 0; i < 2; i++) {
                int idx = tid + i * 256;
                int bk = idx >> 5;
                int bn = (idx & 31) * 4;
                const float4 v = *(const float4*)(Bm + (int64_t)(k0 + bk) * ldb + n0 + bn);
                *(float4*)&Bs[bk][bn] = v;
            }
        }
        __syncthreads();

        #pragma unroll
        for (int k = 0; k < BK; k++) {
            float a[8], b[8];
            *(float4*)&a[0] = *(const float4*)&As[k][tm * 8];
            *(float4*)&a[4] = *(const float4*)&As[k][tm * 8 + 4];
            *(float4*)&b[0] = *(const float4*)&Bs[k][tn * 8];
            *(float4*)&b[4] = *(const float4*)&Bs[k][tn * 8 + 4];
            #pragma unroll
            for (int i = 0; i < 8; i++)
                #pragma unroll
                for (int j = 0; j < 8; j++)
                    acc[i][j] += a[i] * b[j];
        }
        __syncthreads();
    }

    float bv[8];
    #pragma unroll
    for (int j = 0; j < 8; j++) {
        int n = n0 + tn * 8 + j;
        float b = 0.0f;
        if (bias1) b += bias1[n];
        if (bias2) b += bias2[n];
        bv[j] = b;
    }
    #pragma unroll
    for (int i = 0; i < 8; i++) {
        int64_t m = m0 + tm * 8 + i;
        float o[8];
        #pragma unroll
        for (int j = 0; j < 8; j++) {
            float v = acc[i][j] + bv[j];
            if (ACT == 1) v = tanhf(v);
            o[j] = v;
        }
        *(float4*)(C + m * ldc + n0 + tn * 8)     = make_float4(o[0], o[1], o[2], o[3]);
        *(float4*)(C + m * ldc + n0 + tn * 8 + 4) = make_float4(o[4], o[5], o[6], o[7]);
    }
}

// ---------------------------------------------------------------------------
// Fused pipelined recurrence.  grid = 192 blocks (role = bid>>6, b = bid&63),
// 512 threads, 1 block/CU -> all co-resident.  Dataflow A -> B -> C only.
__global__ __launch_bounds__(512)
__attribute__((amdgpu_waves_per_eu(2, 2)))
void fused_rec_kernel(
    const float* __restrict__ Ag0,
    const uint4* __restrict__ Wpk,
    const float* __restrict__ h0l,
    const float* __restrict__ c0l,
    const float* __restrict__ bih,
    const float* __restrict__ bhh,
    float* __restrict__ cat,
    unsigned int* __restrict__ HX,     // [B*T*H] stamped h0 (write-once)
    float* __restrict__ AGX,           // [AGDEPTH][64][1024] Ag1 ring
    unsigned int* __restrict__ AGS,    // [64][AGDEPTH] release stamps
    unsigned int* __restrict__ CCTR)   // [64] C progress counters
{
    const int bid  = blockIdx.x;
    const int role = bid >> 6;          // 0=A, 1=B, 2=C
    const int b    = bid & 63;
    const int tid  = threadIdx.x;
    const int s    = tid >> 8;
    const int q    = tid & 255;

    __shared__ __align__(16) uint4          Wlh[ULDS * 2 * 512];   // 128 KB
    __shared__ __align__(16) float          gsh2[2 * GATES];       // 8 KB
    __shared__ __align__(16) unsigned short hsh[HT];               // 512 B

    const uint4* Wb = Wpk + (role == 0 ? 0 : (role == 1 ? 2 : 1)) * 32768;

    uint4 wreg[2 * UREG];
    #pragma unroll
    for (int u = 0; u < UREG; u++) {
        wreg[2 * u]     = Wb[(u * 2 + 0) * 512 + tid];
        wreg[2 * u + 1] = Wb[(u * 2 + 1) * 512 + tid];
    }
    #pragma unroll
    for (int v = 0; v < ULDS; v++) {
        Wlh[(v * 2 + 0) * 512 + tid] = Wb[((UREG + v) * 2 + 0) * 512 + tid];
        Wlh[(v * 2 + 1) * 512 + tid] = Wb[((UREG + v) * 2 + 1) * 512 + tid];
    }
    const uint4* __restrict__ Ws = Wb + (UREG + ULDS) * 2 * 512;
    const uint4* hp4 = (const uint4*)hsh;
    const int hb = 16 * s;

    if (role == 0) {
        // ---------------- Role A: layer-0 recurrence (R10) + publish ------
        if (tid < HT) {
            half_t hv = (half_t)h0l[b * HT + tid];
            hsh[tid] = __builtin_bit_cast(unsigned short, hv);
        }
        float c = (tid < HT) ? c0l[b * HT + tid] : 0.0f;
        const float* AgB = Ag0 + (int64_t)b * TT * GATES;
        unsigned int* HXb = HX + (int64_t)b * TT * HT;
        __syncthreads();

        #pragma unroll 1
        for (int st = 0; st < TT; st++) {
            float4 aval = make_float4(0.f, 0.f, 0.f, 0.f);
            if (s == 0) aval = *(const float4*)(AgB + (int64_t)st * GATES + 4 * q);
            float a0 = 0.f, a1 = 0.f, a2 = 0.f, a3 = 0.f;
            DOT_PHASE();
            a0 += aval.x; a1 += aval.y; a2 += aval.z; a3 += aval.w;
            *(float4*)&gsh2[s * GATES + 4 * q] = make_float4(a0, a1, a2, a3);
            WG_BARRIER();
            if (tid < HT) {
                float gi = gsh2[tid]          + gsh2[GATES + tid];
                float gf = gsh2[HT + tid]     + gsh2[GATES + HT + tid];
                float gg = gsh2[2 * HT + tid] + gsh2[GATES + 2 * HT + tid];
                float go = gsh2[3 * HT + tid] + gsh2[GATES + 3 * HT + tid];
                c = fast_sig(gf) * c + fast_sig(gi) * fast_tanh(gg);
                float h = fast_sig(go) * fast_tanh(c);
                half_t hh = (half_t)h;
                unsigned short hb16 = __builtin_bit_cast(unsigned short, hh);
                hsh[tid] = hb16;
                atomicExch(HXb + (int64_t)st * HT + tid,
                           ((unsigned)(st + 1) << 16) | (unsigned)hb16);
            }
            WG_BARRIER();
        }
    } else if (role == 1) {
        // ---------------- Role B: layer-1 input matvec --------------------
        float bi_ = 0.f, bf_ = 0.f, bg_ = 0.f, bo_ = 0.f;
        if (tid < HT) {
            bi_ = bih[GATES + tid]          + bhh[GATES + tid];
            bf_ = bih[GATES + HT + tid]     + bhh[GATES + HT + tid];
            bg_ = bih[GATES + 2 * HT + tid] + bhh[GATES + 2 * HT + tid];
            bo_ = bih[GATES + 3 * HT + tid] + bhh[GATES + 3 * HT + tid];
        }
        const unsigned int* HXb = HX + (int64_t)b * TT * HT;
        __syncthreads();

        #pragma unroll 1
        for (int st = 0; st < TT; st++) {
            // ring back-pressure: ensure C consumed slot before reuse
            if ((st & 3) == 0 && st >= AGDEPTH && tid == 0) {
                while (scload(&CCTR[b]) < (unsigned)(st - (AGDEPTH - 4))) {}
            }
            // poll h0_t (write-once stamped words)
            if (tid < HT) {
                const unsigned int* src = HXb + (int64_t)st * HT + tid;
                unsigned int w = scload(src);
                while ((w >> 16) != (unsigned)(st + 1)) w = scload(src);
                hsh[tid] = (unsigned short)(w & 0xffffu);
            }
            WG_BARRIER();
            float a0 = 0.f, a1 = 0.f, a2 = 0.f, a3 = 0.f;
            DOT_PHASE();
            *(float4*)&gsh2[s * GATES + 4 * q] = make_float4(a0, a1, a2, a3);
            WG_BARRIER();
            if (tid < HT) {
                f32x4 v;
                v[0] = gsh2[tid]          + gsh2[GATES + tid]          + bi_;
                v[1] = gsh2[HT + tid]     + gsh2[GATES + HT + tid]     + bf_;
                v[2] = gsh2[2 * HT + tid] + gsh2[GATES + 2 * HT + tid] + bg_;
                v[3] = gsh2[3 * HT + tid] + gsh2[GATES + 3 * HT + tid] + bo_;
                int slot = st & (AGDEPTH - 1);
                scstore4(AGX + ((int64_t)(slot * 64 + b) * 1024 + 4 * tid), v);
                asm volatile("s_waitcnt vmcnt(0)" ::: "memory");
            }
            WG_BARRIER();
            if (tid == 0)
                atomicExch(&AGS[b * AGDEPTH + (st & (AGDEPTH - 1))],
                           (unsigned)(st + 1));
        }
    } else {
        // ---------------- Role C: layer-1 recurrence ----------------------
        if (tid < HT) {
            half_t hv = (half_t)h0l[BB * HT + b * HT + tid];
            hsh[tid] = __builtin_bit_cast(unsigned short, hv);
        }
        float c = (tid < HT) ? c0l[BB * HT + b * HT + tid] : 0.0f;
        float ac0 = 0.f, ac1 = 0.f, ac2 = 0.f, ac3 = 0.f;
        __syncthreads();
        if (tid < HT) {       // preload Ag1(0)
            while (scload(&AGS[b * AGDEPTH + 0]) != 1u) {}
            f32x4 v = scload4(AGX + ((int64_t)b * 1024 + 4 * tid));
            ac0 = v[0]; ac1 = v[1]; ac2 = v[2]; ac3 = v[3];
        }
        WG_BARRIER();

        #pragma unroll 1
        for (int st = 0; st < TT; st++) {
            float a0 = 0.f, a1 = 0.f, a2 = 0.f, a3 = 0.f;
            DOT_PHASE();
            *(float4*)&gsh2[s * GATES + 4 * q] = make_float4(a0, a1, a2, a3);
            WG_BARRIER();
            if (tid < HT) {
                float gi = gsh2[tid]          + gsh2[GATES + tid]          + ac0;
                float gf = gsh2[HT + tid]     + gsh2[GATES + HT + tid]     + ac1;
                float gg = gsh2[2 * HT + tid] + gsh2[GATES + 2 * HT + tid] + ac2;
                float go = gsh2[3 * HT + tid] + gsh2[GATES + 3 * HT + tid] + ac3;
                c = fast_sig(gf) * c + fast_sig(gi) * fast_tanh(gg);
                float h = fast_sig(go) * fast_tanh(c);
                half_t hh = (half_t)h;
                hsh[tid] = __builtin_bit_cast(unsigned short, hh);
                cat[((int64_t)b * TT + st) * (2 * HT) + tid] = h;
                // prefetch next step's Ag1 (B runs ahead -> usually 1 RTT)
                if (st + 1 < TT) {
                    int sl = (st + 1) & (AGDEPTH - 1);
                    while (scload(&AGS[b * AGDEPTH + sl]) != (unsigned)(st + 2)) {}
                    f32x4 v = scload4(AGX + ((int64_t)(sl * 64 + b) * 1024 + 4 * tid));
                    ac0 = v[0]; ac1 = v[1]; ac2 = v[2]; ac3 = v[3];
                }
            }
            if ((st & 3) == 3 && tid == 256)
                atomicExch(&CCTR[b], (unsigned)(st + 1));
            WG_BARRIER();
        }
    }
}

// ---------------------------------------------------------------------------
__global__ __launch_bounds__(256) void softmax512_kernel(float* __restrict__ S)
{
    int row = blockIdx.x * 4 + (threadIdx.x >> 6);
    int lane = threadIdx.x & 63;
    float* p = S + (int64_t)row * 512 + lane * 8;
    float4 v0 = *(float4*)p;
    float4 v1 = *(float4*)(p + 4);
    float m = fmaxf(fmaxf(fmaxf(v0.x, v0.y), fmaxf(v0.z, v0.w)),
                    fmaxf(fmaxf(v1.x, v1.y), fmaxf(v1.z, v1.w)));
    #pragma unroll
    for (int off = 32; off; off >>= 1) m = fmaxf(m, __shfl_xor(m, off));
    v0.x = __expf(v0.x - m); v0.y = __expf(v0.y - m);
    v0.z = __expf(v0.z - m); v0.w = __expf(v0.w - m);
    v1.x = __expf(v1.x - m); v1.y = __expf(v1.y - m);
    v1.z = __expf(v1.z - m); v1.w = __expf(v1.w - m);
    float s = v0.x + v0.y + v0.z + v0.w + v1.x + v1.y + v1.z + v1.w;
    #pragma unroll
    for (int off = 32; off; off >>= 1) s += __shfl_xor(s, off);
    float inv = 1.0f / s;
    v0.x *= inv; v0.y *= inv; v0.z *= inv; v0.w *= inv;
    v1.x *= inv; v1.y *= inv; v1.z *= inv; v1.w *= inv;
    *(float4*)p = v0;
    *(float4*)(p + 4) = v1;
}

__global__ __launch_bounds__(256) void values_kernel(
    const float* __restrict__ Q, const float* __restrict__ L, float* __restrict__ V)
{
    int row = blockIdx.x * 4 + (threadIdx.x >> 6);
    int lane = threadIdx.x & 63;
    float2 q = *(const float2*)(Q + (int64_t)row * OO + lane * 2);
    float2 l = *(const float2*)(L + (int64_t)row * OO + lane * 2);
    float s = q.x * l.x + q.y * l.y;
    #pragma unroll
    for (int off = 32; off; off >>= 1) s += __shfl_xor(s, off);
    if (lane == 0) V[row] = s;
}

// ---------------------------------------------------------------------------
extern "C" void kernel_launch(void* const* d_in, const int* in_sizes, int n_in,
                              void* d_out, int out_size, void* d_ws, size_t ws_size,
                              hipStream_t stream)
{
    const float* enc      = (const float*)d_in[0];
    const float* h0       = (const float*)d_in[1];
    const float* c0       = (const float*)d_in[2];
    const int*   actions  = (const int*)  d_in[3];
    const float* emb_t    = (const float*)d_in[4];
    const float* Wih      = (const float*)d_in[5];
    const float* Whh      = (const float*)d_in[6];
    const float* bih      = (const float*)d_in[7];
    const float* bhh      = (const float*)d_in[8];
    const float* W_attn   = (const float*)d_in[9];
    const float* b_attn   = (const float*)d_in[10];
    const float* W_concat = (const float*)d_in[11];
    const float* b_concat = (const float*)d_in[12];
    const float* W_out    = (const float*)d_in[13];
    const float* W_critic = (const float*)d_in[14];
    const float* b_critic = (const float*)d_in[15];
    (void)in_sizes; (void)n_in; (void)out_size; (void)ws_size;

    const int M = BB * TT;                 // 32768

    float* out    = (float*)d_out;
    float* dact   = out;
    float* logits = out + M;
    float* values = out + M + (int64_t)M * OO;

    float* ws    = (float*)d_ws;
    float* gates = ws;                       // Ag0, 128 MB
    float* xbuf  = ws + 33554432;            // emb -> (zeroed) -> HX -> dec
    float* cat   = ws + 41943040;            // [M,512]: h1 | ctx
    float* keysR = ws + 58720256;
    float* keys  = keysR;
    uint4* Wpkh  = (uint4*)keysR;            // 1.5 MB; dead before keys
    float* AGX   = ws + 59500000;            // 4 MB ring (dead keys region)
    unsigned int* AGS  = (unsigned int*)(ws + 60600000);
    unsigned int* CCTR = AGS + 64 * AGDEPTH;
    unsigned int* HX   = (unsigned int*)xbuf;
    float* scores = gates;
    float* qv     = gates;
    float* dec    = xbuf;

    const int64_t LW = (int64_t)GATES * HT;
    (void)LW;

    // 1) embedding -> xbuf, + decoder_action
    hipLaunchKernelGGL(embed_kernel, dim3(M), dim3(256), 0, stream,
                       actions, emb_t, xbuf, dact);
    // 2) repack Whh0/Whh1/Wih1 to fp16 R10 layout
    hipLaunchKernelGGL(repack_w_kernel, dim3(384), dim3(256), 0, stream,
                       Whh, Wih, Wpkh);
    // 3) layer-0 input GEMM: gates = emb @ Wih0^T + bih0 + bhh0
    hipLaunchKernelGGL((mfma_gemm_kernel<true, 0>), dim3(8, 256, 1), dim3(256), 0, stream,
                       xbuf, Wih, gates, HT, HT, HT, GATES,
                       (int64_t)0, (int64_t)0, (int64_t)0, bih, bhh);
    // 4) zero h0-exchange buffer (emb consumed) + ring stamps + counters
    hipLaunchKernelGGL(hxzero_kernel, dim3(8192), dim3(256), 0, stream,
                       (uint4*)HX, AGS, CCTR);
    // 5) fused pipelined recurrence: L0 rec || L1 input || L1 rec
    hipLaunchKernelGGL(fused_rec_kernel, dim3(192), dim3(512), 0, stream,
                       gates, Wpkh, h0, c0, bih, bhh, cat, HX, AGX, AGS, CCTR);
    // 6) keys = enc @ W_attn^T + b_attn
    hipLaunchKernelGGL((mfma_gemm_kernel<true, 0>), dim3(2, 256, 1), dim3(256), 0, stream,
                       enc, W_attn, keys, HT, HT, HT, HT,
                       (int64_t)0, (int64_t)0, (int64_t)0, b_attn, (const float*)nullptr);
    // 7) scores[b] = out[b] @ keys[b]^T  (fp32)
    hipLaunchKernelGGL((gemm128_kernel<true, 0>), dim3(4, 4, BB), dim3(256), 0, stream,
                       cat, keys, scores, HT, 2 * HT, HT, TT,
                       (int64_t)TT * 2 * HT, (int64_t)TT * HT, (int64_t)TT * TT,
                       (const float*)nullptr, (const float*)nullptr);
    // 8) softmax
    hipLaunchKernelGGL(softmax512_kernel, dim3(M / 4), dim3(256), 0, stream, scores);
    // 9) ctx[b] = P[b] @ enc[b] -> cat[:,256:]
    hipLaunchKernelGGL((gemm128_kernel<false, 0>), dim3(2, 4, BB), dim3(256), 0, stream,
                       scores, enc, cat + HT, TT, TT, HT, 2 * HT,
                       (int64_t)TT * TT, (int64_t)TT * HT, (int64_t)TT * 2 * HT,
                       (const float*)nullptr, (const float*)nullptr);
    // 10) dec = tanh(cat @ W_concat^T + b_concat)
    hipLaunchKernelGGL((mfma_gemm_kernel<true, 1>), dim3(2, 256, 1), dim3(256), 0, stream,
                       cat, W_concat, dec, 2 * HT, 2 * HT, 2 * HT, HT,
                       (int64_t)0, (int64_t)0, (int64_t)0, b_concat, (const float*)nullptr);
    // 11) logits = dec @ W_out^T  (fp32)
    hipLaunchKernelGGL((gemm128_kernel<true, 0>), dim3(1, 256, 1), dim3(256), 0, stream,
                       dec, W_out, logits, HT, HT, HT, OO,
                       (int64_t)0, (int64_t)0, (int64_t)0,
                       (const float*)nullptr, (const float*)nullptr);
    // 12) qv = logits @ W_critic^T + b_critic  (fp32)
    hipLaunchKernelGGL((gemm128_kernel<true, 0>), dim3(1, 256, 1), dim3(256), 0, stream,
                       logits, W_critic, qv, OO, OO, OO, OO,
                       (int64_t)0, (int64_t)0, (int64_t)0, b_critic, (const float*)nullptr);
    // 13) values
    hipLaunchKernelGGL(values_kernel, dim3(M / 4), dim3(256), 0, stream,
                       qv, logits, values);
}

// Round 11
// 1816.910 us; speedup vs baseline: 1.1700x; 1.0590x over previous
//
#include <hip/hip_runtime.h>
#include <stdint.h>

// Problem constants
#define BB   64
#define TT   512
#define HT   256
#define OO   128
#define GATES 1024   // 4*H

// R20 = R19 (fused pipelined recurrence, 1434us, stage-A-bound) + the two
// dominant fp32 tail GEMMs (scores 17.2GF, ctx 17.2GF) flipped to the proven
// MFMA fp16 kernel (fp32 accumulate).  Expected tail savings ~230us.
// R19 recap: 192 co-resident blocks, one-directional A(L0 rec)->B(L1 input)
// ->C(L1 rec); pipeline runs exactly at stage-A's R10 delivery floor
// (~3470cy/step) with zero sync overhead.
#define PREG 10
#define PLDS 4
#define PSTR 2
#define UREG (2*PREG)
#define ULDS (2*PLDS)
#define AGDEPTH 16

typedef _Float16 half_t;
typedef _Float16 half2_t __attribute__((ext_vector_type(2)));
typedef float    f32x4  __attribute__((ext_vector_type(4)));

__device__ __forceinline__ half2_t h2_(unsigned int x) {
    return __builtin_bit_cast(half2_t, x);
}
#define WG_BARRIER() do { __builtin_amdgcn_s_waitcnt(0xC07F); \
                          __builtin_amdgcn_s_barrier(); } while (0)

__device__ __forceinline__ float fast_sig(float x) {
    return __builtin_amdgcn_rcpf(1.0f + __expf(-x));
}
__device__ __forceinline__ float fast_tanh(float x) {
    float t = __expf(2.0f * x);
    return 1.0f - 2.0f * __builtin_amdgcn_rcpf(t + 1.0f);
}

// system-coherent accesses (read/write the coherence point; proven R17-R19)
__device__ __forceinline__ unsigned int scload(const unsigned int* p) {
    unsigned long long a = (unsigned long long)p;
    unsigned int w;
    asm volatile("global_load_dword %0, %1, off sc0 sc1\n\ts_waitcnt vmcnt(0)"
                 : "=v"(w) : "v"(a) : "memory");
    return w;
}
__device__ __forceinline__ f32x4 scload4(const float* p) {
    unsigned long long a = (unsigned long long)p;
    f32x4 v;
    asm volatile("global_load_dwordx4 %0, %1, off sc0 sc1\n\ts_waitcnt vmcnt(0)"
                 : "=v"(v) : "v"(a) : "memory");
    return v;
}
__device__ __forceinline__ void scstore4(float* p, f32x4 v) {
    unsigned long long a = (unsigned long long)p;
    asm volatile("global_store_dwordx4 %0, %1, off sc0 sc1"
                 :: "v"(a), "v"(v) : "memory");
}

#define PAIR_DOT(wa0, wb0, wa1, wb1, h4)                                  \
    do {                                                                   \
        a0 = __builtin_amdgcn_fdot2(h2_((wa0).x), h2_((h4).x), a0, false); \
        a0 = __builtin_amdgcn_fdot2(h2_((wa0).y), h2_((h4).y), a0, false); \
        a1 = __builtin_amdgcn_fdot2(h2_((wa0).z), h2_((h4).x), a1, false); \
        a1 = __builtin_amdgcn_fdot2(h2_((wa0).w), h2_((h4).y), a1, false); \
        a2 = __builtin_amdgcn_fdot2(h2_((wb0).x), h2_((h4).x), a2, false); \
        a2 = __builtin_amdgcn_fdot2(h2_((wb0).y), h2_((h4).y), a2, false); \
        a3 = __builtin_amdgcn_fdot2(h2_((wb0).z), h2_((h4).x), a3, false); \
        a3 = __builtin_amdgcn_fdot2(h2_((wb0).w), h2_((h4).y), a3, false); \
        a0 = __builtin_amdgcn_fdot2(h2_((wa1).x), h2_((h4).z), a0, false); \
        a0 = __builtin_amdgcn_fdot2(h2_((wa1).y), h2_((h4).w), a0, false); \
        a1 = __builtin_amdgcn_fdot2(h2_((wa1).z), h2_((h4).z), a1, false); \
        a1 = __builtin_amdgcn_fdot2(h2_((wa1).w), h2_((h4).w), a1, false); \
        a2 = __builtin_amdgcn_fdot2(h2_((wb1).x), h2_((h4).z), a2, false); \
        a2 = __builtin_amdgcn_fdot2(h2_((wb1).y), h2_((h4).w), a2, false); \
        a3 = __builtin_amdgcn_fdot2(h2_((wb1).z), h2_((h4).z), a3, false); \
        a3 = __builtin_amdgcn_fdot2(h2_((wb1).w), h2_((h4).w), a3, false); \
    } while (0)

// full dot phase over this thread's 4 gate rows x k-half (R10 verbatim)
#define DOT_PHASE()                                                        \
    do {                                                                   \
        _Pragma("unroll 2")                                                \
        for (int p = 0; p < PSTR; p++) {                                   \
            uint4 wa0 = Ws[(p * 4 + 0) * 512 + tid];                       \
            uint4 wb0 = Ws[(p * 4 + 1) * 512 + tid];                       \
            uint4 wa1 = Ws[(p * 4 + 2) * 512 + tid];                       \
            uint4 wb1 = Ws[(p * 4 + 3) * 512 + tid];                       \
            uint4 h4  = hp4[hb + PREG + PLDS + p];                         \
            PAIR_DOT(wa0, wb0, wa1, wb1, h4);                              \
        }                                                                  \
        _Pragma("unroll")                                                  \
        for (int p = 0; p < PLDS; p++) {                                   \
            uint4 wa0 = Wlh[(p * 4 + 0) * 512 + tid];                      \
            uint4 wb0 = Wlh[(p * 4 + 1) * 512 + tid];                      \
            uint4 wa1 = Wlh[(p * 4 + 2) * 512 + tid];                      \
            uint4 wb1 = Wlh[(p * 4 + 3) * 512 + tid];                      \
            uint4 h4  = hp4[hb + PREG + p];                                \
            PAIR_DOT(wa0, wb0, wa1, wb1, h4);                              \
        }                                                                  \
        _Pragma("unroll")                                                  \
        for (int p = 0; p < PREG; p++) {                                   \
            uint4 h4 = hp4[hb + p];                                        \
            PAIR_DOT(wreg[4 * p], wreg[4 * p + 1],                         \
                     wreg[4 * p + 2], wreg[4 * p + 3], h4);                \
        }                                                                  \
    } while (0)

// ---------------------------------------------------------------------------
__global__ __launch_bounds__(256) void embed_kernel(
    const int* __restrict__ actions, const float* __restrict__ emb_table,
    float* __restrict__ X, float* __restrict__ dact)
{
    int row = blockIdx.x;
    int t = row & (TT - 1);
    int id = (t == 0) ? 0 : actions[row - 1];
    X[(int64_t)row * HT + threadIdx.x] = emb_table[(int64_t)id * HT + threadIdx.x];
    if (threadIdx.x == 0) dact[row] = (float)actions[row];
}

// ---------------------------------------------------------------------------
// Repack 3 weight matrices to the R10 fp16 layout:
// slot 0 = Whh layer0 (role A), slot 1 = Whh layer1 (role C),
// slot 2 = Wih layer1 (role B).
__global__ __launch_bounds__(256) void repack_w_kernel(
    const float* __restrict__ Whh, const float* __restrict__ Wih,
    uint4* __restrict__ Wpkh)
{
    int idx = blockIdx.x * 256 + threadIdx.x;   // 0..98303
    int g   = idx & 32767;
    int l   = idx >> 15;                        // 0..2
    int tid = g & 511;
    int ab  = (g >> 9) & 1;
    int u   = (g >> 10) & 31;
    int s = tid >> 8, q = tid & 255;
    int r0 = 4 * q + 2 * ab;
    int k  = 128 * s + 4 * u;
    const float* base = (l == 0) ? Whh
                      : (l == 1) ? Whh + (int64_t)GATES * HT
                                 : Wih + (int64_t)GATES * HT;
    const float4 a = *(const float4*)(base + (int64_t)r0 * HT + k);
    const float4 b = *(const float4*)(base + (int64_t)(r0 + 1) * HT + k);
    half2_t p0 = {(half_t)a.x, (half_t)a.y};
    half2_t p1 = {(half_t)a.z, (half_t)a.w};
    half2_t p2 = {(half_t)b.x, (half_t)b.y};
    half2_t p3 = {(half_t)b.z, (half_t)b.w};
    uint4 o;
    o.x = __builtin_bit_cast(unsigned int, p0);
    o.y = __builtin_bit_cast(unsigned int, p1);
    o.z = __builtin_bit_cast(unsigned int, p2);
    o.w = __builtin_bit_cast(unsigned int, p3);
    Wpkh[idx] = o;
}

// ---------------------------------------------------------------------------
// Zero the h0 exchange buffer + Ag1 ring stamps + progress counters.
__global__ __launch_bounds__(256) void hxzero_kernel(
    uint4* __restrict__ HX4, unsigned int* __restrict__ AGS,
    unsigned int* __restrict__ CCTR)
{
    int i = blockIdx.x * 256 + threadIdx.x;     // grid 8192 -> 2M uint4
    HX4[i] = make_uint4(0u, 0u, 0u, 0u);
    if (blockIdx.x == 0) {
        for (int k = threadIdx.x; k < 64 * AGDEPTH; k += 256) AGS[k] = 0u;
        if (threadIdx.x < 64) CCTR[threadIdx.x] = 0u;
    }
}

// ---------------------------------------------------------------------------
// MFMA fp16 GEMM: C = act( A @ op(B) + bias1 + bias2 ), fp32 in/out.
template<bool TRANS_B, int ACT>
__global__ __launch_bounds__(256) void mfma_gemm_kernel(
    const float* __restrict__ A, const float* __restrict__ Bm,
    float* __restrict__ C,
    int K, int lda, int ldb, int ldc,
    int64_t sA, int64_t sB, int64_t sC,
    const float* __restrict__ bias1, const float* __restrict__ bias2)
{
    constexpr int BM = 128, BN = 128, BK = 32;
    constexpr int LDT = BK + 8;
    __shared__ __align__(16) half_t Asl[BM * LDT];
    __shared__ __align__(16) half_t Bsl[BN * LDT];

    const int tid  = threadIdx.x;
    const int wave = tid >> 6;
    const int lane = tid & 63;
    const int wm = (wave & 1) * 64;
    const int wn = (wave >> 1) * 64;
    const int m0 = blockIdx.y * BM;
    const int n0 = blockIdx.x * BN;
    A  += (int64_t)blockIdx.z * sA;
    Bm += (int64_t)blockIdx.z * sB;
    C  += (int64_t)blockIdx.z * sC;

    const int fm = lane & 15;
    const int qd = lane >> 4;

    f32x4 acc[4][4] = {};

    for (int k0 = 0; k0 < K; k0 += BK) {
        #pragma unroll
        for (int i = 0; i < 4; i++) {
            int idx = tid + i * 256;
            int r  = idx >> 3;
            int kq = idx & 7;
            float4 v = *(const float4*)(A + (int64_t)(m0 + r) * lda + k0 + kq * 4);
            half_t* d = &Asl[r * LDT + kq * 4];
            d[0] = (half_t)v.x; d[1] = (half_t)v.y;
            d[2] = (half_t)v.z; d[3] = (half_t)v.w;
        }
        if (TRANS_B) {
            #pragma unroll
            for (int i = 0; i < 4; i++) {
                int idx = tid + i * 256;
                int r  = idx >> 3;
                int kq = idx & 7;
                float4 v = *(const float4*)(Bm + (int64_t)(n0 + r) * ldb + k0 + kq * 4);
                half_t* d = &Bsl[r * LDT + kq * 4];
                d[0] = (half_t)v.x; d[1] = (half_t)v.y;
                d[2] = (half_t)v.z; d[3] = (half_t)v.w;
            }
        } else {
            #pragma unroll
            for (int i = 0; i < 4; i++) {
                int idx = tid + i * 256;
                int kk = idx >> 5;
                int nq = idx & 31;
                float4 v = *(const float4*)(Bm + (int64_t)(k0 + kk) * ldb + n0 + nq * 4);
                Bsl[(nq * 4 + 0) * LDT + kk] = (half_t)v.x;
                Bsl[(nq * 4 + 1) * LDT + kk] = (half_t)v.y;
                Bsl[(nq * 4 + 2) * LDT + kk] = (half_t)v.z;
                Bsl[(nq * 4 + 3) * LDT + kk] = (half_t)v.w;
            }
        }
        __syncthreads();

        typedef _Float16 f16x8 __attribute__((ext_vector_type(8)));
        f16x8 af[4], bf[4];
        #pragma unroll
        for (int t = 0; t < 4; t++)
            af[t] = *(const f16x8*)&Asl[(wm + t * 16 + fm) * LDT + qd * 8];
        #pragma unroll
        for (int t = 0; t < 4; t++)
            bf[t] = *(const f16x8*)&Bsl[(wn + t * 16 + fm) * LDT + qd * 8];
        #pragma unroll
        for (int mt = 0; mt < 4; mt++)
            #pragma unroll
            for (int nt = 0; nt < 4; nt++)
                acc[mt][nt] = __builtin_amdgcn_mfma_f32_16x16x32_f16(
                                  af[mt], bf[nt], acc[mt][nt], 0, 0, 0);
        __syncthreads();
    }

    #pragma unroll
    for (int nt = 0; nt < 4; nt++) {
        int n = n0 + wn + nt * 16 + fm;
        float bv = 0.0f;
        if (bias1) bv += bias1[n];
        if (bias2) bv += bias2[n];
        #pragma unroll
        for (int mt = 0; mt < 4; mt++) {
            #pragma unroll
            for (int r = 0; r < 4; r++) {
                int m = m0 + wm + mt * 16 + qd * 4 + r;
                float v = acc[mt][nt][r] + bv;
                if (ACT == 1) v = tanhf(v);
                C[(int64_t)m * ldc + n] = v;
            }
        }
    }
}

// ---------------------------------------------------------------------------
// Generic fp32 tiled GEMM (output chain precision).
template<bool TRANS_B, int ACT>
__global__ __launch_bounds__(256) void gemm128_kernel(
    const float* __restrict__ A, const float* __restrict__ Bm,
    float* __restrict__ C,
    int K, int lda, int ldb, int ldc,
    int64_t sA, int64_t sB, int64_t sC,
    const float* __restrict__ bias1, const float* __restrict__ bias2)
{
    constexpr int BM = 128, BN = 128, BK = 16;
    __shared__ __align__(16) float As[BK][BM + 4];
    __shared__ __align__(16) float Bs[BK][BN + 4];

    const int tid = threadIdx.x;
    const int m0 = blockIdx.y * BM;
    const int n0 = blockIdx.x * BN;
    A  += (int64_t)blockIdx.z * sA;
    Bm += (int64_t)blockIdx.z * sB;
    C  += (int64_t)blockIdx.z * sC;

    const int tm = tid & 15;
    const int tn = tid >> 4;

    float acc[8][8] = {};

    for (int k0 = 0; k0 < K; k0 += BK) {
        #pragma unroll
        for (int i = 0; i < 2; i++) {
            int idx = tid + i * 256;
            int ar = idx >> 2;
            int ak = (idx & 3) * 4;
            const float4 v = *(const float4*)(A + (int64_t)(m0 + ar) * lda + k0 + ak);
            As[ak + 0][ar] = v.x; As[ak + 1][ar] = v.y;
            As[ak + 2][ar] = v.z; As[ak + 3][ar] = v.w;
        }
        if (TRANS_B) {
            #pragma unroll
            for (int i = 0; i < 2; i++) {
                int idx = tid + i * 256;
                int br = idx >> 2;
                int bk = (idx & 3) * 4;
                const float4 v = *(const float4*)(Bm + (int64_t)(n0 + br) * ldb + k0 + bk);
                Bs[bk + 0][br] = v.x; Bs[bk + 1][br] = v.y;
                Bs[bk + 2][br] = v.z; Bs[bk + 3][br] = v.w;
            }
        } else {
            #pragma unroll
            for (int i = 0; i < 2; i++) {
                int idx = tid + i * 256;
                int bk = idx >> 5;
                int bn = (idx & 31) * 4;
                const float4 v = *(const float4*)(Bm + (int64_t)(k0 + bk) * ldb + n0 + bn);
                *(float4*)&Bs[bk][bn] = v;
            }
        }
        __syncthreads();

        #pragma unroll
        for (int k = 0; k < BK; k++) {
            float a[8], b[8];
            *(float4*)&a[0] = *(const float4*)&As[k][tm * 8];
            *(float4*)&a[4] = *(const float4*)&As[k][tm * 8 + 4];
            *(float4*)&b[0] = *(const float4*)&Bs[k][tn * 8];
            *(float4*)&b[4] = *(const float4*)&Bs[k][tn * 8 + 4];
            #pragma unroll
            for (int i = 0; i < 8; i++)
                #pragma unroll
                for (int j = 0; j < 8; j++)
                    acc[i][j] += a[i] * b[j];
        }
        __syncthreads();
    }

    float bv[8];
    #pragma unroll
    for (int j = 0; j < 8; j++) {
        int n = n0 + tn * 8 + j;
        float b = 0.0f;
        if (bias1) b += bias1[n];
        if (bias2) b += bias2[n];
        bv[j] = b;
    }
    #pragma unroll
    for (int i = 0; i < 8; i++) {
        int64_t m = m0 + tm * 8 + i;
        float o[8];
        #pragma unroll
        for (int j = 0; j < 8; j++) {
            float v = acc[i][j] + bv[j];
            if (ACT == 1) v = tanhf(v);
            o[j] = v;
        }
        *(float4*)(C + m * ldc + n0 + tn * 8)     = make_float4(o[0], o[1], o[2], o[3]);
        *(float4*)(C + m * ldc + n0 + tn * 8 + 4) = make_float4(o[4], o[5], o[6], o[7]);
    }
}

// ---------------------------------------------------------------------------
// Fused pipelined recurrence.  grid = 192 blocks (role = bid>>6, b = bid&63),
// 512 threads, 1 block/CU -> all co-resident.  Dataflow A -> B -> C only.
__global__ __launch_bounds__(512)
__attribute__((amdgpu_waves_per_eu(2, 2)))
void fused_rec_kernel(
    const float* __restrict__ Ag0,
    const uint4* __restrict__ Wpk,
    const float* __restrict__ h0l,
    const float* __restrict__ c0l,
    const float* __restrict__ bih,
    const float* __restrict__ bhh,
    float* __restrict__ cat,
    unsigned int* __restrict__ HX,     // [B*T*H] stamped h0 (write-once)
    float* __restrict__ AGX,           // [AGDEPTH][64][1024] Ag1 ring
    unsigned int* __restrict__ AGS,    // [64][AGDEPTH] release stamps
    unsigned int* __restrict__ CCTR)   // [64] C progress counters
{
    const int bid  = blockIdx.x;
    const int role = bid >> 6;          // 0=A, 1=B, 2=C
    const int b    = bid & 63;
    const int tid  = threadIdx.x;
    const int s    = tid >> 8;
    const int q    = tid & 255;

    __shared__ __align__(16) uint4          Wlh[ULDS * 2 * 512];   // 128 KB
    __shared__ __align__(16) float          gsh2[2 * GATES];       // 8 KB
    __shared__ __align__(16) unsigned short hsh[HT];               // 512 B

    const uint4* Wb = Wpk + (role == 0 ? 0 : (role == 1 ? 2 : 1)) * 32768;

    uint4 wreg[2 * UREG];
    #pragma unroll
    for (int u = 0; u < UREG; u++) {
        wreg[2 * u]     = Wb[(u * 2 + 0) * 512 + tid];
        wreg[2 * u + 1] = Wb[(u * 2 + 1) * 512 + tid];
    }
    #pragma unroll
    for (int v = 0; v < ULDS; v++) {
        Wlh[(v * 2 + 0) * 512 + tid] = Wb[((UREG + v) * 2 + 0) * 512 + tid];
        Wlh[(v * 2 + 1) * 512 + tid] = Wb[((UREG + v) * 2 + 1) * 512 + tid];
    }
    const uint4* __restrict__ Ws = Wb + (UREG + ULDS) * 2 * 512;
    const uint4* hp4 = (const uint4*)hsh;
    const int hb = 16 * s;

    if (role == 0) {
        // ---------------- Role A: layer-0 recurrence (R10) + publish ------
        if (tid < HT) {
            half_t hv = (half_t)h0l[b * HT + tid];
            hsh[tid] = __builtin_bit_cast(unsigned short, hv);
        }
        float c = (tid < HT) ? c0l[b * HT + tid] : 0.0f;
        const float* AgB = Ag0 + (int64_t)b * TT * GATES;
        unsigned int* HXb = HX + (int64_t)b * TT * HT;
        __syncthreads();

        #pragma unroll 1
        for (int st = 0; st < TT; st++) {
            float4 aval = make_float4(0.f, 0.f, 0.f, 0.f);
            if (s == 0) aval = *(const float4*)(AgB + (int64_t)st * GATES + 4 * q);
            float a0 = 0.f, a1 = 0.f, a2 = 0.f, a3 = 0.f;
            DOT_PHASE();
            a0 += aval.x; a1 += aval.y; a2 += aval.z; a3 += aval.w;
            *(float4*)&gsh2[s * GATES + 4 * q] = make_float4(a0, a1, a2, a3);
            WG_BARRIER();
            if (tid < HT) {
                float gi = gsh2[tid]          + gsh2[GATES + tid];
                float gf = gsh2[HT + tid]     + gsh2[GATES + HT + tid];
                float gg = gsh2[2 * HT + tid] + gsh2[GATES + 2 * HT + tid];
                float go = gsh2[3 * HT + tid] + gsh2[GATES + 3 * HT + tid];
                c = fast_sig(gf) * c + fast_sig(gi) * fast_tanh(gg);
                float h = fast_sig(go) * fast_tanh(c);
                half_t hh = (half_t)h;
                unsigned short hb16 = __builtin_bit_cast(unsigned short, hh);
                hsh[tid] = hb16;
                atomicExch(HXb + (int64_t)st * HT + tid,
                           ((unsigned)(st + 1) << 16) | (unsigned)hb16);
            }
            WG_BARRIER();
        }
    } else if (role == 1) {
        // ---------------- Role B: layer-1 input matvec --------------------
        float bi_ = 0.f, bf_ = 0.f, bg_ = 0.f, bo_ = 0.f;
        if (tid < HT) {
            bi_ = bih[GATES + tid]          + bhh[GATES + tid];
            bf_ = bih[GATES + HT + tid]     + bhh[GATES + HT + tid];
            bg_ = bih[GATES + 2 * HT + tid] + bhh[GATES + 2 * HT + tid];
            bo_ = bih[GATES + 3 * HT + tid] + bhh[GATES + 3 * HT + tid];
        }
        const unsigned int* HXb = HX + (int64_t)b * TT * HT;
        __syncthreads();

        #pragma unroll 1
        for (int st = 0; st < TT; st++) {
            // ring back-pressure: ensure C consumed slot before reuse
            if ((st & 3) == 0 && st >= AGDEPTH && tid == 0) {
                while (scload(&CCTR[b]) < (unsigned)(st - (AGDEPTH - 4))) {}
            }
            // poll h0_t (write-once stamped words)
            if (tid < HT) {
                const unsigned int* src = HXb + (int64_t)st * HT + tid;
                unsigned int w = scload(src);
                while ((w >> 16) != (unsigned)(st + 1)) w = scload(src);
                hsh[tid] = (unsigned short)(w & 0xffffu);
            }
            WG_BARRIER();
            float a0 = 0.f, a1 = 0.f, a2 = 0.f, a3 = 0.f;
            DOT_PHASE();
            *(float4*)&gsh2[s * GATES + 4 * q] = make_float4(a0, a1, a2, a3);
            WG_BARRIER();
            if (tid < HT) {
                f32x4 v;
                v[0] = gsh2[tid]          + gsh2[GATES + tid]          + bi_;
                v[1] = gsh2[HT + tid]     + gsh2[GATES + HT + tid]     + bf_;
                v[2] = gsh2[2 * HT + tid] + gsh2[GATES + 2 * HT + tid] + bg_;
                v[3] = gsh2[3 * HT + tid] + gsh2[GATES + 3 * HT + tid] + bo_;
                int slot = st & (AGDEPTH - 1);
                scstore4(AGX + ((int64_t)(slot * 64 + b) * 1024 + 4 * tid), v);
                asm volatile("s_waitcnt vmcnt(0)" ::: "memory");
            }
            WG_BARRIER();
            if (tid == 0)
                atomicExch(&AGS[b * AGDEPTH + (st & (AGDEPTH - 1))],
                           (unsigned)(st + 1));
        }
    } else {
        // ---------------- Role C: layer-1 recurrence ----------------------
        if (tid < HT) {
            half_t hv = (half_t)h0l[BB * HT + b * HT + tid];
            hsh[tid] = __builtin_bit_cast(unsigned short, hv);
        }
        float c = (tid < HT) ? c0l[BB * HT + b * HT + tid] : 0.0f;
        float ac0 = 0.f, ac1 = 0.f, ac2 = 0.f, ac3 = 0.f;
        __syncthreads();
        if (tid < HT) {       // preload Ag1(0)
            while (scload(&AGS[b * AGDEPTH + 0]) != 1u) {}
            f32x4 v = scload4(AGX + ((int64_t)b * 1024 + 4 * tid));
            ac0 = v[0]; ac1 = v[1]; ac2 = v[2]; ac3 = v[3];
        }
        WG_BARRIER();

        #pragma unroll 1
        for (int st = 0; st < TT; st++) {
            float a0 = 0.f, a1 = 0.f, a2 = 0.f, a3 = 0.f;
            DOT_PHASE();
            *(float4*)&gsh2[s * GATES + 4 * q] = make_float4(a0, a1, a2, a3);
            WG_BARRIER();
            if (tid < HT) {
                float gi = gsh2[tid]          + gsh2[GATES + tid]          + ac0;
                float gf = gsh2[HT + tid]     + gsh2[GATES + HT + tid]     + ac1;
                float gg = gsh2[2 * HT + tid] + gsh2[GATES + 2 * HT + tid] + ac2;
                float go = gsh2[3 * HT + tid] + gsh2[GATES + 3 * HT + tid] + ac3;
                c = fast_sig(gf) * c + fast_sig(gi) * fast_tanh(gg);
                float h = fast_sig(go) * fast_tanh(c);
                half_t hh = (half_t)h;
                hsh[tid] = __builtin_bit_cast(unsigned short, hh);
                cat[((int64_t)b * TT + st) * (2 * HT) + tid] = h;
                // prefetch next step's Ag1 (B runs ahead -> usually 1 RTT)
                if (st + 1 < TT) {
                    int sl = (st + 1) & (AGDEPTH - 1);
                    while (scload(&AGS[b * AGDEPTH + sl]) != (unsigned)(st + 2)) {}
                    f32x4 v = scload4(AGX + ((int64_t)(sl * 64 + b) * 1024 + 4 * tid));
                    ac0 = v[0]; ac1 = v[1]; ac2 = v[2]; ac3 = v[3];
                }
            }
            if ((st & 3) == 3 && tid == 256)
                atomicExch(&CCTR[b], (unsigned)(st + 1));
            WG_BARRIER();
        }
    }
}

// ---------------------------------------------------------------------------
__global__ __launch_bounds__(256) void softmax512_kernel(float* __restrict__ S)
{
    int row = blockIdx.x * 4 + (threadIdx.x >> 6);
    int lane = threadIdx.x & 63;
    float* p = S + (int64_t)row * 512 + lane * 8;
    float4 v0 = *(float4*)p;
    float4 v1 = *(float4*)(p + 4);
    float m = fmaxf(fmaxf(fmaxf(v0.x, v0.y), fmaxf(v0.z, v0.w)),
                    fmaxf(fmaxf(v1.x, v1.y), fmaxf(v1.z, v1.w)));
    #pragma unroll
    for (int off = 32; off; off >>= 1) m = fmaxf(m, __shfl_xor(m, off));
    v0.x = __expf(v0.x - m); v0.y = __expf(v0.y - m);
    v0.z = __expf(v0.z - m); v0.w = __expf(v0.w - m);
    v1.x = __expf(v1.x - m); v1.y = __expf(v1.y - m);
    v1.z = __expf(v1.z - m); v1.w = __expf(v1.w - m);
    float s = v0.x + v0.y + v0.z + v0.w + v1.x + v1.y + v1.z + v1.w;
    #pragma unroll
    for (int off = 32; off; off >>= 1) s += __shfl_xor(s, off);
    float inv = 1.0f / s;
    v0.x *= inv; v0.y *= inv; v0.z *= inv; v0.w *= inv;
    v1.x *= inv; v1.y *= inv; v1.z *= inv; v1.w *= inv;
    *(float4*)p = v0;
    *(float4*)(p + 4) = v1;
}

__global__ __launch_bounds__(256) void values_kernel(
    const float* __restrict__ Q, const float* __restrict__ L, float* __restrict__ V)
{
    int row = blockIdx.x * 4 + (threadIdx.x >> 6);
    int lane = threadIdx.x & 63;
    float2 q = *(const float2*)(Q + (int64_t)row * OO + lane * 2);
    float2 l = *(const float2*)(L + (int64_t)row * OO + lane * 2);
    float s = q.x * l.x + q.y * l.y;
    #pragma unroll
    for (int off = 32; off; off >>= 1) s += __shfl_xor(s, off);
    if (lane == 0) V[row] = s;
}

// ---------------------------------------------------------------------------
extern "C" void kernel_launch(void* const* d_in, const int* in_sizes, int n_in,
                              void* d_out, int out_size, void* d_ws, size_t ws_size,
                              hipStream_t stream)
{
    const float* enc      = (const float*)d_in[0];
    const float* h0       = (const float*)d_in[1];
    const float* c0       = (const float*)d_in[2];
    const int*   actions  = (const int*)  d_in[3];
    const float* emb_t    = (const float*)d_in[4];
    const float* Wih      = (const float*)d_in[5];
    const float* Whh      = (const float*)d_in[6];
    const float* bih      = (const float*)d_in[7];
    const float* bhh      = (const float*)d_in[8];
    const float* W_attn   = (const float*)d_in[9];
    const float* b_attn   = (const float*)d_in[10];
    const float* W_concat = (const float*)d_in[11];
    const float* b_concat = (const float*)d_in[12];
    const float* W_out    = (const float*)d_in[13];
    const float* W_critic = (const float*)d_in[14];
    const float* b_critic = (const float*)d_in[15];
    (void)in_sizes; (void)n_in; (void)out_size; (void)ws_size;

    const int M = BB * TT;                 // 32768

    float* out    = (float*)d_out;
    float* dact   = out;
    float* logits = out + M;
    float* values = out + M + (int64_t)M * OO;

    float* ws    = (float*)d_ws;
    float* gates = ws;                       // Ag0, 128 MB
    float* xbuf  = ws + 33554432;            // emb -> (zeroed) -> HX -> dec
    float* cat   = ws + 41943040;            // [M,512]: h1 | ctx
    float* keysR = ws + 58720256;
    float* keys  = keysR;
    uint4* Wpkh  = (uint4*)keysR;            // 1.5 MB; dead before keys
    float* AGX   = ws + 59500000;            // 4 MB ring (dead keys region)
    unsigned int* AGS  = (unsigned int*)(ws + 60600000);
    unsigned int* CCTR = AGS + 64 * AGDEPTH;
    unsigned int* HX   = (unsigned int*)xbuf;
    float* scores = gates;
    float* qv     = gates;
    float* dec    = xbuf;

    // 1) embedding -> xbuf, + decoder_action
    hipLaunchKernelGGL(embed_kernel, dim3(M), dim3(256), 0, stream,
                       actions, emb_t, xbuf, dact);
    // 2) repack Whh0/Whh1/Wih1 to fp16 R10 layout
    hipLaunchKernelGGL(repack_w_kernel, dim3(384), dim3(256), 0, stream,
                       Whh, Wih, Wpkh);
    // 3) layer-0 input GEMM: gates = emb @ Wih0^T + bih0 + bhh0
    hipLaunchKernelGGL((mfma_gemm_kernel<true, 0>), dim3(8, 256, 1), dim3(256), 0, stream,
                       xbuf, Wih, gates, HT, HT, HT, GATES,
                       (int64_t)0, (int64_t)0, (int64_t)0, bih, bhh);
    // 4) zero h0-exchange buffer (emb consumed) + ring stamps + counters
    hipLaunchKernelGGL(hxzero_kernel, dim3(8192), dim3(256), 0, stream,
                       (uint4*)HX, AGS, CCTR);
    // 5) fused pipelined recurrence: L0 rec || L1 input || L1 rec
    hipLaunchKernelGGL(fused_rec_kernel, dim3(192), dim3(512), 0, stream,
                       gates, Wpkh, h0, c0, bih, bhh, cat, HX, AGX, AGS, CCTR);
    // 6) keys = enc @ W_attn^T + b_attn (MFMA fp16)
    hipLaunchKernelGGL((mfma_gemm_kernel<true, 0>), dim3(2, 256, 1), dim3(256), 0, stream,
                       enc, W_attn, keys, HT, HT, HT, HT,
                       (int64_t)0, (int64_t)0, (int64_t)0, b_attn, (const float*)nullptr);
    // 7) scores[b] = out[b] @ keys[b]^T  (MFMA fp16, fp32 accumulate — R20)
    hipLaunchKernelGGL((mfma_gemm_kernel<true, 0>), dim3(4, 4, BB), dim3(256), 0, stream,
                       cat, keys, scores, HT, 2 * HT, HT, TT,
                       (int64_t)TT * 2 * HT, (int64_t)TT * HT, (int64_t)TT * TT,
                       (const float*)nullptr, (const float*)nullptr);
    // 8) softmax
    hipLaunchKernelGGL(softmax512_kernel, dim3(M / 4), dim3(256), 0, stream, scores);
    // 9) ctx[b] = P[b] @ enc[b] -> cat[:,256:]  (MFMA fp16 — R20)
    hipLaunchKernelGGL((mfma_gemm_kernel<false, 0>), dim3(2, 4, BB), dim3(256), 0, stream,
                       scores, enc, cat + HT, TT, TT, HT, 2 * HT,
                       (int64_t)TT * TT, (int64_t)TT * HT, (int64_t)TT * 2 * HT,
                       (const float*)nullptr, (const float*)nullptr);
    // 10) dec = tanh(cat @ W_concat^T + b_concat)
    hipLaunchKernelGGL((mfma_gemm_kernel<true, 1>), dim3(2, 256, 1), dim3(256), 0, stream,
                       cat, W_concat, dec, 2 * HT, 2 * HT, 2 * HT, HT,
                       (int64_t)0, (int64_t)0, (int64_t)0, b_concat, (const float*)nullptr);
    // 11) logits = dec @ W_out^T  (fp32 — output path)
    hipLaunchKernelGGL((gemm128_kernel<true, 0>), dim3(1, 256, 1), dim3(256), 0, stream,
                       dec, W_out, logits, HT, HT, HT, OO,
                       (int64_t)0, (int64_t)0, (int64_t)0,
                       (const float*)nullptr, (const float*)nullptr);
    // 12) qv = logits @ W_critic^T + b_critic  (fp32 — output path)
    hipLaunchKernelGGL((gemm128_kernel<true, 0>), dim3(1, 256, 1), dim3(256), 0, stream,
                       logits, W_critic, qv, OO, OO, OO, OO,
                       (int64_t)0, (int64_t)0, (int64_t)0, b_critic, (const float*)nullptr);
    // 13) values
    hipLaunchKernelGGL(values_kernel, dim3(M / 4), dim3(256), 0, stream,
                       qv, logits, values);
}

// Round 12
// 1614.711 us; speedup vs baseline: 1.3165x; 1.1252x over previous
//
#include <hip/hip_runtime.h>
#include <stdint.h>

// Problem constants
#define BB   64
#define TT   512
#define HT   256
#define OO   128
#define GATES 1024   // 4*H

// R21 = R20 with the fused pipeline's handshakes collapsed to ~1 RTT each.
// R20 measured fused = 1434us = 6723cy/step vs 3470cy stage floor: ~3200cy
// of sync overhead (B: poll + store-drain-flag; C: serial AGS-poll + AGX-load
// in the tid<HT tail).  R21: (1) B publishes Ag1 as stamp-in-word u64
// atomicExch (no drain, no flag array); (2) C's idle waves (4-7) batch-load
// + validate Ag1(t+1) into parity-double-buffered agsh LDS during the tail,
// overlapping the gate math; (3) B loses its third barrier.
#define PREG 10
#define PLDS 4
#define PSTR 2
#define UREG (2*PREG)
#define ULDS (2*PLDS)
#define AGDEPTH 16

typedef _Float16 half_t;
typedef _Float16 half2_t __attribute__((ext_vector_type(2)));
typedef float    f32x4  __attribute__((ext_vector_type(4)));
typedef unsigned long long u64;

__device__ __forceinline__ half2_t h2_(unsigned int x) {
    return __builtin_bit_cast(half2_t, x);
}
#define WG_BARRIER() do { __builtin_amdgcn_s_waitcnt(0xC07F); \
                          __builtin_amdgcn_s_barrier(); } while (0)

__device__ __forceinline__ float fast_sig(float x) {
    return __builtin_amdgcn_rcpf(1.0f + __expf(-x));
}
__device__ __forceinline__ float fast_tanh(float x) {
    float t = __expf(2.0f * x);
    return 1.0f - 2.0f * __builtin_amdgcn_rcpf(t + 1.0f);
}

// system-coherent accesses (read the coherence point; proven R17-R20)
__device__ __forceinline__ unsigned int scload(const unsigned int* p) {
    unsigned long long a = (unsigned long long)p;
    unsigned int w;
    asm volatile("global_load_dword %0, %1, off sc0 sc1\n\ts_waitcnt vmcnt(0)"
                 : "=v"(w) : "v"(a) : "memory");
    return w;
}
__device__ __forceinline__ u64 scload64(const u64* p) {
    unsigned long long a = (unsigned long long)p;
    u64 w;
    asm volatile("global_load_dwordx2 %0, %1, off sc0 sc1\n\ts_waitcnt vmcnt(0)"
                 : "=v"(w) : "v"(a) : "memory");
    return w;
}
// batch: 4 loads in flight, ONE vmcnt wait -> 1 RTT total
__device__ __forceinline__ void scload64x4(
    const u64* p0, const u64* p1, const u64* p2, const u64* p3,
    u64& w0, u64& w1, u64& w2, u64& w3)
{
    unsigned long long a0 = (unsigned long long)p0;
    unsigned long long a1 = (unsigned long long)p1;
    unsigned long long a2 = (unsigned long long)p2;
    unsigned long long a3 = (unsigned long long)p3;
    asm volatile(
        "global_load_dwordx2 %0, %4, off sc0 sc1\n\t"
        "global_load_dwordx2 %1, %5, off sc0 sc1\n\t"
        "global_load_dwordx2 %2, %6, off sc0 sc1\n\t"
        "global_load_dwordx2 %3, %7, off sc0 sc1\n\t"
        "s_waitcnt vmcnt(0)"
        : "=v"(w0), "=v"(w1), "=v"(w2), "=v"(w3)
        : "v"(a0), "v"(a1), "v"(a2), "v"(a3) : "memory");
}

#define PAIR_DOT(wa0, wb0, wa1, wb1, h4)                                  \
    do {                                                                   \
        a0 = __builtin_amdgcn_fdot2(h2_((wa0).x), h2_((h4).x), a0, false); \
        a0 = __builtin_amdgcn_fdot2(h2_((wa0).y), h2_((h4).y), a0, false); \
        a1 = __builtin_amdgcn_fdot2(h2_((wa0).z), h2_((h4).x), a1, false); \
        a1 = __builtin_amdgcn_fdot2(h2_((wa0).w), h2_((h4).y), a1, false); \
        a2 = __builtin_amdgcn_fdot2(h2_((wb0).x), h2_((h4).x), a2, false); \
        a2 = __builtin_amdgcn_fdot2(h2_((wb0).y), h2_((h4).y), a2, false); \
        a3 = __builtin_amdgcn_fdot2(h2_((wb0).z), h2_((h4).x), a3, false); \
        a3 = __builtin_amdgcn_fdot2(h2_((wb0).w), h2_((h4).y), a3, false); \
        a0 = __builtin_amdgcn_fdot2(h2_((wa1).x), h2_((h4).z), a0, false); \
        a0 = __builtin_amdgcn_fdot2(h2_((wa1).y), h2_((h4).w), a0, false); \
        a1 = __builtin_amdgcn_fdot2(h2_((wa1).z), h2_((h4).z), a1, false); \
        a1 = __builtin_amdgcn_fdot2(h2_((wa1).w), h2_((h4).w), a1, false); \
        a2 = __builtin_amdgcn_fdot2(h2_((wb1).x), h2_((h4).z), a2, false); \
        a2 = __builtin_amdgcn_fdot2(h2_((wb1).y), h2_((h4).w), a2, false); \
        a3 = __builtin_amdgcn_fdot2(h2_((wb1).z), h2_((h4).z), a3, false); \
        a3 = __builtin_amdgcn_fdot2(h2_((wb1).w), h2_((h4).w), a3, false); \
    } while (0)

// full dot phase over this thread's 4 gate rows x k-half (R10 verbatim)
#define DOT_PHASE()                                                        \
    do {                                                                   \
        _Pragma("unroll 2")                                                \
        for (int p = 0; p < PSTR; p++) {                                   \
            uint4 wa0 = Ws[(p * 4 + 0) * 512 + tid];                       \
            uint4 wb0 = Ws[(p * 4 + 1) * 512 + tid];                       \
            uint4 wa1 = Ws[(p * 4 + 2) * 512 + tid];                       \
            uint4 wb1 = Ws[(p * 4 + 3) * 512 + tid];                       \
            uint4 h4  = hp4[hb + PREG + PLDS + p];                         \
            PAIR_DOT(wa0, wb0, wa1, wb1, h4);                              \
        }                                                                  \
        _Pragma("unroll")                                                  \
        for (int p = 0; p < PLDS; p++) {                                   \
            uint4 wa0 = Wlh[(p * 4 + 0) * 512 + tid];                      \
            uint4 wb0 = Wlh[(p * 4 + 1) * 512 + tid];                      \
            uint4 wa1 = Wlh[(p * 4 + 2) * 512 + tid];                      \
            uint4 wb1 = Wlh[(p * 4 + 3) * 512 + tid];                      \
            uint4 h4  = hp4[hb + PREG + p];                                \
            PAIR_DOT(wa0, wb0, wa1, wb1, h4);                              \
        }                                                                  \
        _Pragma("unroll")                                                  \
        for (int p = 0; p < PREG; p++) {                                   \
            uint4 h4 = hp4[hb + p];                                        \
            PAIR_DOT(wreg[4 * p], wreg[4 * p + 1],                         \
                     wreg[4 * p + 2], wreg[4 * p + 3], h4);                \
        }                                                                  \
    } while (0)

// ---------------------------------------------------------------------------
__global__ __launch_bounds__(256) void embed_kernel(
    const int* __restrict__ actions, const float* __restrict__ emb_table,
    float* __restrict__ X, float* __restrict__ dact)
{
    int row = blockIdx.x;
    int t = row & (TT - 1);
    int id = (t == 0) ? 0 : actions[row - 1];
    X[(int64_t)row * HT + threadIdx.x] = emb_table[(int64_t)id * HT + threadIdx.x];
    if (threadIdx.x == 0) dact[row] = (float)actions[row];
}

// ---------------------------------------------------------------------------
// Repack 3 weight matrices to the R10 fp16 layout:
// slot 0 = Whh layer0 (role A), slot 1 = Whh layer1 (role C),
// slot 2 = Wih layer1 (role B).
__global__ __launch_bounds__(256) void repack_w_kernel(
    const float* __restrict__ Whh, const float* __restrict__ Wih,
    uint4* __restrict__ Wpkh)
{
    int idx = blockIdx.x * 256 + threadIdx.x;   // 0..98303
    int g   = idx & 32767;
    int l   = idx >> 15;                        // 0..2
    int tid = g & 511;
    int ab  = (g >> 9) & 1;
    int u   = (g >> 10) & 31;
    int s = tid >> 8, q = tid & 255;
    int r0 = 4 * q + 2 * ab;
    int k  = 128 * s + 4 * u;
    const float* base = (l == 0) ? Whh
                      : (l == 1) ? Whh + (int64_t)GATES * HT
                                 : Wih + (int64_t)GATES * HT;
    const float4 a = *(const float4*)(base + (int64_t)r0 * HT + k);
    const float4 b = *(const float4*)(base + (int64_t)(r0 + 1) * HT + k);
    half2_t p0 = {(half_t)a.x, (half_t)a.y};
    half2_t p1 = {(half_t)a.z, (half_t)a.w};
    half2_t p2 = {(half_t)b.x, (half_t)b.y};
    half2_t p3 = {(half_t)b.z, (half_t)b.w};
    uint4 o;
    o.x = __builtin_bit_cast(unsigned int, p0);
    o.y = __builtin_bit_cast(unsigned int, p1);
    o.z = __builtin_bit_cast(unsigned int, p2);
    o.w = __builtin_bit_cast(unsigned int, p3);
    Wpkh[idx] = o;
}

// ---------------------------------------------------------------------------
// Zero the h0 exchange buffer + Ag1 stamped ring + progress counters.
__global__ __launch_bounds__(256) void hxzero_kernel(
    uint4* __restrict__ HX4, u64* __restrict__ AGU,
    unsigned int* __restrict__ CCTR)
{
    int i = blockIdx.x * 256 + threadIdx.x;     // grid 8192 -> 2M
    HX4[i] = make_uint4(0u, 0u, 0u, 0u);
    if (i < AGDEPTH * 64 * 1024) AGU[i] = 0ull;
    if (i < 64) CCTR[i] = 0u;
}

// ---------------------------------------------------------------------------
// MFMA fp16 GEMM: C = act( A @ op(B) + bias1 + bias2 ), fp32 in/out.
template<bool TRANS_B, int ACT>
__global__ __launch_bounds__(256) void mfma_gemm_kernel(
    const float* __restrict__ A, const float* __restrict__ Bm,
    float* __restrict__ C,
    int K, int lda, int ldb, int ldc,
    int64_t sA, int64_t sB, int64_t sC,
    const float* __restrict__ bias1, const float* __restrict__ bias2)
{
    constexpr int BM = 128, BN = 128, BK = 32;
    constexpr int LDT = BK + 8;
    __shared__ __align__(16) half_t Asl[BM * LDT];
    __shared__ __align__(16) half_t Bsl[BN * LDT];

    const int tid  = threadIdx.x;
    const int wave = tid >> 6;
    const int lane = tid & 63;
    const int wm = (wave & 1) * 64;
    const int wn = (wave >> 1) * 64;
    const int m0 = blockIdx.y * BM;
    const int n0 = blockIdx.x * BN;
    A  += (int64_t)blockIdx.z * sA;
    Bm += (int64_t)blockIdx.z * sB;
    C  += (int64_t)blockIdx.z * sC;

    const int fm = lane & 15;
    const int qd = lane >> 4;

    f32x4 acc[4][4] = {};

    for (int k0 = 0; k0 < K; k0 += BK) {
        #pragma unroll
        for (int i = 0; i < 4; i++) {
            int idx = tid + i * 256;
            int r  = idx >> 3;
            int kq = idx & 7;
            float4 v = *(const float4*)(A + (int64_t)(m0 + r) * lda + k0 + kq * 4);
            half_t* d = &Asl[r * LDT + kq * 4];
            d[0] = (half_t)v.x; d[1] = (half_t)v.y;
            d[2] = (half_t)v.z; d[3] = (half_t)v.w;
        }
        if (TRANS_B) {
            #pragma unroll
            for (int i = 0; i < 4; i++) {
                int idx = tid + i * 256;
                int r  = idx >> 3;
                int kq = idx & 7;
                float4 v = *(const float4*)(Bm + (int64_t)(n0 + r) * ldb + k0 + kq * 4);
                half_t* d = &Bsl[r * LDT + kq * 4];
                d[0] = (half_t)v.x; d[1] = (half_t)v.y;
                d[2] = (half_t)v.z; d[3] = (half_t)v.w;
            }
        } else {
            #pragma unroll
            for (int i = 0; i < 4; i++) {
                int idx = tid + i * 256;
                int kk = idx >> 5;
                int nq = idx & 31;
                float4 v = *(const float4*)(Bm + (int64_t)(k0 + kk) * ldb + n0 + nq * 4);
                Bsl[(nq * 4 + 0) * LDT + kk] = (half_t)v.x;
                Bsl[(nq * 4 + 1) * LDT + kk] = (half_t)v.y;
                Bsl[(nq * 4 + 2) * LDT + kk] = (half_t)v.z;
                Bsl[(nq * 4 + 3) * LDT + kk] = (half_t)v.w;
            }
        }
        __syncthreads();

        typedef _Float16 f16x8 __attribute__((ext_vector_type(8)));
        f16x8 af[4], bf[4];
        #pragma unroll
        for (int t = 0; t < 4; t++)
            af[t] = *(const f16x8*)&Asl[(wm + t * 16 + fm) * LDT + qd * 8];
        #pragma unroll
        for (int t = 0; t < 4; t++)
            bf[t] = *(const f16x8*)&Bsl[(wn + t * 16 + fm) * LDT + qd * 8];
        #pragma unroll
        for (int mt = 0; mt < 4; mt++)
            #pragma unroll
            for (int nt = 0; nt < 4; nt++)
                acc[mt][nt] = __builtin_amdgcn_mfma_f32_16x16x32_f16(
                                  af[mt], bf[nt], acc[mt][nt], 0, 0, 0);
        __syncthreads();
    }

    #pragma unroll
    for (int nt = 0; nt < 4; nt++) {
        int n = n0 + wn + nt * 16 + fm;
        float bv = 0.0f;
        if (bias1) bv += bias1[n];
        if (bias2) bv += bias2[n];
        #pragma unroll
        for (int mt = 0; mt < 4; mt++) {
            #pragma unroll
            for (int r = 0; r < 4; r++) {
                int m = m0 + wm + mt * 16 + qd * 4 + r;
                float v = acc[mt][nt][r] + bv;
                if (ACT == 1) v = tanhf(v);
                C[(int64_t)m * ldc + n] = v;
            }
        }
    }
}

// ---------------------------------------------------------------------------
// Generic fp32 tiled GEMM (output chain precision).
template<bool TRANS_B, int ACT>
__global__ __launch_bounds__(256) void gemm128_kernel(
    const float* __restrict__ A, const float* __restrict__ Bm,
    float* __restrict__ C,
    int K, int lda, int ldb, int ldc,
    int64_t sA, int64_t sB, int64_t sC,
    const float* __restrict__ bias1, const float* __restrict__ bias2)
{
    constexpr int BM = 128, BN = 128, BK = 16;
    __shared__ __align__(16) float As[BK][BM + 4];
    __shared__ __align__(16) float Bs[BK][BN + 4];

    const int tid = threadIdx.x;
    const int m0 = blockIdx.y * BM;
    const int n0 = blockIdx.x * BN;
    A  += (int64_t)blockIdx.z * sA;
    Bm += (int64_t)blockIdx.z * sB;
    C  += (int64_t)blockIdx.z * sC;

    const int tm = tid & 15;
    const int tn = tid >> 4;

    float acc[8][8] = {};

    for (int k0 = 0; k0 < K; k0 += BK) {
        #pragma unroll
        for (int i = 0; i < 2; i++) {
            int idx = tid + i * 256;
            int ar = idx >> 2;
            int ak = (idx & 3) * 4;
            const float4 v = *(const float4*)(A + (int64_t)(m0 + ar) * lda + k0 + ak);
            As[ak + 0][ar] = v.x; As[ak + 1][ar] = v.y;
            As[ak + 2][ar] = v.z; As[ak + 3][ar] = v.w;
        }
        if (TRANS_B) {
            #pragma unroll
            for (int i = 0; i < 2; i++) {
                int idx = tid + i * 256;
                int br = idx >> 2;
                int bk = (idx & 3) * 4;
                const float4 v = *(const float4*)(Bm + (int64_t)(n0 + br) * ldb + k0 + bk);
                Bs[bk + 0][br] = v.x; Bs[bk + 1][br] = v.y;
                Bs[bk + 2][br] = v.z; Bs[bk + 3][br] = v.w;
            }
        } else {
            #pragma unroll
            for (int i = 0; i < 2; i++) {
                int idx = tid + i * 256;
                int bk = idx >> 5;
                int bn = (idx & 31) * 4;
                const float4 v = *(const float4*)(Bm + (int64_t)(k0 + bk) * ldb + n0 + bn);
                *(float4*)&Bs[bk][bn] = v;
            }
        }
        __syncthreads();

        #pragma unroll
        for (int k = 0; k < BK; k++) {
            float a[8], b[8];
            *(float4*)&a[0] = *(const float4*)&As[k][tm * 8];
            *(float4*)&a[4] = *(const float4*)&As[k][tm * 8 + 4];
            *(float4*)&b[0] = *(const float4*)&Bs[k][tn * 8];
            *(float4*)&b[4] = *(const float4*)&Bs[k][tn * 8 + 4];
            #pragma unroll
            for (int i = 0; i < 8; i++)
                #pragma unroll
                for (int j = 0; j < 8; j++)
                    acc[i][j] += a[i] * b[j];
        }
        __syncthreads();
    }

    float bv[8];
    #pragma unroll
    for (int j = 0; j < 8; j++) {
        int n = n0 + tn * 8 + j;
        float b = 0.0f;
        if (bias1) b += bias1[n];
        if (bias2) b += bias2[n];
        bv[j] = b;
    }
    #pragma unroll
    for (int i = 0; i < 8; i++) {
        int64_t m = m0 + tm * 8 + i;
        float o[8];
        #pragma unroll
        for (int j = 0; j < 8; j++) {
            float v = acc[i][j] + bv[j];
            if (ACT == 1) v = tanhf(v);
            o[j] = v;
        }
        *(float4*)(C + m * ldc + n0 + tn * 8)     = make_float4(o[0], o[1], o[2], o[3]);
        *(float4*)(C + m * ldc + n0 + tn * 8 + 4) = make_float4(o[4], o[5], o[6], o[7]);
    }
}

// ---------------------------------------------------------------------------
// Fused pipelined recurrence.  grid = 192 blocks (role = bid>>6, b = bid&63),
// 512 threads, 1 block/CU -> all co-resident.  Dataflow A -> B -> C only.
__global__ __launch_bounds__(512)
__attribute__((amdgpu_waves_per_eu(2, 2)))
void fused_rec_kernel(
    const float* __restrict__ Ag0,
    const uint4* __restrict__ Wpk,
    const float* __restrict__ h0l,
    const float* __restrict__ c0l,
    const float* __restrict__ bih,
    const float* __restrict__ bhh,
    float* __restrict__ cat,
    unsigned int* __restrict__ HX,     // [B*T*H] stamped h0 (write-once)
    u64* __restrict__ AGU,             // [AGDEPTH][64][1024] stamped Ag1 ring
    unsigned int* __restrict__ CCTR)   // [64] C progress counters
{
    const int bid  = blockIdx.x;
    const int role = bid >> 6;          // 0=A, 1=B, 2=C
    const int b    = bid & 63;
    const int tid  = threadIdx.x;
    const int s    = tid >> 8;
    const int q    = tid & 255;

    __shared__ __align__(16) uint4          Wlh[ULDS * 2 * 512];   // 128 KB
    __shared__ __align__(16) float          gsh2[2 * GATES];       // 8 KB
    __shared__ __align__(16) float          agsh[2][GATES];        // 8 KB (role C)
    __shared__ __align__(16) unsigned short hsh[HT];               // 512 B

    const uint4* Wb = Wpk + (role == 0 ? 0 : (role == 1 ? 2 : 1)) * 32768;

    uint4 wreg[2 * UREG];
    #pragma unroll
    for (int u = 0; u < UREG; u++) {
        wreg[2 * u]     = Wb[(u * 2 + 0) * 512 + tid];
        wreg[2 * u + 1] = Wb[(u * 2 + 1) * 512 + tid];
    }
    #pragma unroll
    for (int v = 0; v < ULDS; v++) {
        Wlh[(v * 2 + 0) * 512 + tid] = Wb[((UREG + v) * 2 + 0) * 512 + tid];
        Wlh[(v * 2 + 1) * 512 + tid] = Wb[((UREG + v) * 2 + 1) * 512 + tid];
    }
    const uint4* __restrict__ Ws = Wb + (UREG + ULDS) * 2 * 512;
    const uint4* hp4 = (const uint4*)hsh;
    const int hb = 16 * s;

    if (role == 0) {
        // ---------------- Role A: layer-0 recurrence (R10) + publish ------
        if (tid < HT) {
            half_t hv = (half_t)h0l[b * HT + tid];
            hsh[tid] = __builtin_bit_cast(unsigned short, hv);
        }
        float c = (tid < HT) ? c0l[b * HT + tid] : 0.0f;
        const float* AgB = Ag0 + (int64_t)b * TT * GATES;
        unsigned int* HXb = HX + (int64_t)b * TT * HT;
        __syncthreads();

        #pragma unroll 1
        for (int st = 0; st < TT; st++) {
            float4 aval = make_float4(0.f, 0.f, 0.f, 0.f);
            if (s == 0) aval = *(const float4*)(AgB + (int64_t)st * GATES + 4 * q);
            float a0 = 0.f, a1 = 0.f, a2 = 0.f, a3 = 0.f;
            DOT_PHASE();
            a0 += aval.x; a1 += aval.y; a2 += aval.z; a3 += aval.w;
            *(float4*)&gsh2[s * GATES + 4 * q] = make_float4(a0, a1, a2, a3);
            WG_BARRIER();
            if (tid < HT) {
                float gi = gsh2[tid]          + gsh2[GATES + tid];
                float gf = gsh2[HT + tid]     + gsh2[GATES + HT + tid];
                float gg = gsh2[2 * HT + tid] + gsh2[GATES + 2 * HT + tid];
                float go = gsh2[3 * HT + tid] + gsh2[GATES + 3 * HT + tid];
                c = fast_sig(gf) * c + fast_sig(gi) * fast_tanh(gg);
                float h = fast_sig(go) * fast_tanh(c);
                half_t hh = (half_t)h;
                unsigned short hb16 = __builtin_bit_cast(unsigned short, hh);
                hsh[tid] = hb16;
                atomicExch(HXb + (int64_t)st * HT + tid,
                           ((unsigned)(st + 1) << 16) | (unsigned)hb16);
            }
            WG_BARRIER();
        }
    } else if (role == 1) {
        // ---------------- Role B: layer-1 input matvec --------------------
        float bi_ = 0.f, bf_ = 0.f, bg_ = 0.f, bo_ = 0.f;
        if (tid < HT) {
            bi_ = bih[GATES + tid]          + bhh[GATES + tid];
            bf_ = bih[GATES + HT + tid]     + bhh[GATES + HT + tid];
            bg_ = bih[GATES + 2 * HT + tid] + bhh[GATES + 2 * HT + tid];
            bo_ = bih[GATES + 3 * HT + tid] + bhh[GATES + 3 * HT + tid];
        }
        const unsigned int* HXb = HX + (int64_t)b * TT * HT;
        __syncthreads();

        #pragma unroll 1
        for (int st = 0; st < TT; st++) {
            // ring back-pressure: ensure C consumed slot before reuse
            if ((st & 3) == 0 && st >= AGDEPTH && tid == 0) {
                while (scload(&CCTR[b]) < (unsigned)(st - (AGDEPTH - 4))) {}
            }
            // poll h0_t (write-once stamped words, 1 RTT when ready)
            if (tid < HT) {
                const unsigned int* src = HXb + (int64_t)st * HT + tid;
                unsigned int w = scload(src);
                while ((w >> 16) != (unsigned)(st + 1)) w = scload(src);
                hsh[tid] = (unsigned short)(w & 0xffffu);
            }
            WG_BARRIER();
            float a0 = 0.f, a1 = 0.f, a2 = 0.f, a3 = 0.f;
            DOT_PHASE();
            *(float4*)&gsh2[s * GATES + 4 * q] = make_float4(a0, a1, a2, a3);
            WG_BARRIER();
            // publish Ag1 as stamp-in-word u64 atomics (fire-and-forget:
            // no vmcnt drain, no flag array)
            if (tid < HT) {
                u64 hi = ((u64)(st + 1)) << 32;
                u64* dst = AGU + (int64_t)((st & (AGDEPTH - 1)) * 64 + b) * 1024;
                float v0 = gsh2[tid]          + gsh2[GATES + tid]          + bi_;
                float v1 = gsh2[HT + tid]     + gsh2[GATES + HT + tid]     + bf_;
                float v2 = gsh2[2 * HT + tid] + gsh2[GATES + 2 * HT + tid] + bg_;
                float v3 = gsh2[3 * HT + tid] + gsh2[GATES + 3 * HT + tid] + bo_;
                atomicExch(&dst[tid],          hi | (u64)__float_as_uint(v0));
                atomicExch(&dst[HT + tid],     hi | (u64)__float_as_uint(v1));
                atomicExch(&dst[2 * HT + tid], hi | (u64)__float_as_uint(v2));
                atomicExch(&dst[3 * HT + tid], hi | (u64)__float_as_uint(v3));
            }
            // no third barrier: next poll writes hsh, ordered by barrier #1
        }
    } else {
        // ---------------- Role C: layer-1 recurrence ----------------------
        if (tid < HT) {
            half_t hv = (half_t)h0l[BB * HT + b * HT + tid];
            hsh[tid] = __builtin_bit_cast(unsigned short, hv);
        }
        float c = (tid < HT) ? c0l[BB * HT + b * HT + tid] : 0.0f;
        __syncthreads();
        // preload Ag1(0) into agsh[0] (waves 4-7, batch-validated)
        if (tid >= 256) {
            int i = tid - 256;
            const u64* src = AGU + (int64_t)b * 1024;
            u64 w0, w1, w2, w3;
            scload64x4(src + i, src + i + 256, src + i + 512, src + i + 768,
                       w0, w1, w2, w3);
            while ((unsigned)(w0 >> 32) != 1u) w0 = scload64(src + i);
            while ((unsigned)(w1 >> 32) != 1u) w1 = scload64(src + i + 256);
            while ((unsigned)(w2 >> 32) != 1u) w2 = scload64(src + i + 512);
            while ((unsigned)(w3 >> 32) != 1u) w3 = scload64(src + i + 768);
            agsh[0][i]       = __uint_as_float((unsigned)w0);
            agsh[0][i + 256] = __uint_as_float((unsigned)w1);
            agsh[0][i + 512] = __uint_as_float((unsigned)w2);
            agsh[0][i + 768] = __uint_as_float((unsigned)w3);
        }
        WG_BARRIER();

        #pragma unroll 1
        for (int st = 0; st < TT; st++) {
            float a0 = 0.f, a1 = 0.f, a2 = 0.f, a3 = 0.f;
            DOT_PHASE();
            *(float4*)&gsh2[s * GATES + 4 * q] = make_float4(a0, a1, a2, a3);
            WG_BARRIER();
            if (tid < HT) {
                const float* ag = agsh[st & 1];
                float gi = gsh2[tid]          + gsh2[GATES + tid]          + ag[tid];
                float gf = gsh2[HT + tid]     + gsh2[GATES + HT + tid]     + ag[HT + tid];
                float gg = gsh2[2 * HT + tid] + gsh2[GATES + 2 * HT + tid] + ag[2 * HT + tid];
                float go = gsh2[3 * HT + tid] + gsh2[GATES + 3 * HT + tid] + ag[3 * HT + tid];
                c = fast_sig(gf) * c + fast_sig(gi) * fast_tanh(gg);
                float h = fast_sig(go) * fast_tanh(c);
                hsh[tid] = __builtin_bit_cast(unsigned short, (half_t)h);
                cat[((int64_t)b * TT + st) * (2 * HT) + tid] = h;
            } else {
                // idle waves: release progress + prefetch Ag1(st+1) into
                // agsh[(st+1)&1], overlapped with the gate math above
                if ((st & 3) == 3 && tid == 256)
                    atomicExch(&CCTR[b], (unsigned)(st + 1));
                if (st + 1 < TT) {
                    int i = tid - 256;
                    int sl = (st + 1) & (AGDEPTH - 1);
                    unsigned expect = (unsigned)(st + 2);
                    const u64* src = AGU + (int64_t)(sl * 64 + b) * 1024;
                    u64 w0, w1, w2, w3;
                    scload64x4(src + i, src + i + 256, src + i + 512, src + i + 768,
                               w0, w1, w2, w3);
                    while ((unsigned)(w0 >> 32) != expect) w0 = scload64(src + i);
                    while ((unsigned)(w1 >> 32) != expect) w1 = scload64(src + i + 256);
                    while ((unsigned)(w2 >> 32) != expect) w2 = scload64(src + i + 512);
                    while ((unsigned)(w3 >> 32) != expect) w3 = scload64(src + i + 768);
                    float* d = agsh[(st + 1) & 1];
                    d[i]       = __uint_as_float((unsigned)w0);
                    d[i + 256] = __uint_as_float((unsigned)w1);
                    d[i + 512] = __uint_as_float((unsigned)w2);
                    d[i + 768] = __uint_as_float((unsigned)w3);
                }
            }
            WG_BARRIER();
        }
    }
}

// ---------------------------------------------------------------------------
__global__ __launch_bounds__(256) void softmax512_kernel(float* __restrict__ S)
{
    int row = blockIdx.x * 4 + (threadIdx.x >> 6);
    int lane = threadIdx.x & 63;
    float* p = S + (int64_t)row * 512 + lane * 8;
    float4 v0 = *(float4*)p;
    float4 v1 = *(float4*)(p + 4);
    float m = fmaxf(fmaxf(fmaxf(v0.x, v0.y), fmaxf(v0.z, v0.w)),
                    fmaxf(fmaxf(v1.x, v1.y), fmaxf(v1.z, v1.w)));
    #pragma unroll
    for (int off = 32; off; off >>= 1) m = fmaxf(m, __shfl_xor(m, off));
    v0.x = __expf(v0.x - m); v0.y = __expf(v0.y - m);
    v0.z = __expf(v0.z - m); v0.w = __expf(v0.w - m);
    v1.x = __expf(v1.x - m); v1.y = __expf(v1.y - m);
    v1.z = __expf(v1.z - m); v1.w = __expf(v1.w - m);
    float s = v0.x + v0.y + v0.z + v0.w + v1.x + v1.y + v1.z + v1.w;
    #pragma unroll
    for (int off = 32; off; off >>= 1) s += __shfl_xor(s, off);
    float inv = 1.0f / s;
    v0.x *= inv; v0.y *= inv; v0.z *= inv; v0.w *= inv;
    v1.x *= inv; v1.y *= inv; v1.z *= inv; v1.w *= inv;
    *(float4*)p = v0;
    *(float4*)(p + 4) = v1;
}

__global__ __launch_bounds__(256) void values_kernel(
    const float* __restrict__ Q, const float* __restrict__ L, float* __restrict__ V)
{
    int row = blockIdx.x * 4 + (threadIdx.x >> 6);
    int lane = threadIdx.x & 63;
    float2 q = *(const float2*)(Q + (int64_t)row * OO + lane * 2);
    float2 l = *(const float2*)(L + (int64_t)row * OO + lane * 2);
    float s = q.x * l.x + q.y * l.y;
    #pragma unroll
    for (int off = 32; off; off >>= 1) s += __shfl_xor(s, off);
    if (lane == 0) V[row] = s;
}

// ---------------------------------------------------------------------------
extern "C" void kernel_launch(void* const* d_in, const int* in_sizes, int n_in,
                              void* d_out, int out_size, void* d_ws, size_t ws_size,
                              hipStream_t stream)
{
    const float* enc      = (const float*)d_in[0];
    const float* h0       = (const float*)d_in[1];
    const float* c0       = (const float*)d_in[2];
    const int*   actions  = (const int*)  d_in[3];
    const float* emb_t    = (const float*)d_in[4];
    const float* Wih      = (const float*)d_in[5];
    const float* Whh      = (const float*)d_in[6];
    const float* bih      = (const float*)d_in[7];
    const float* bhh      = (const float*)d_in[8];
    const float* W_attn   = (const float*)d_in[9];
    const float* b_attn   = (const float*)d_in[10];
    const float* W_concat = (const float*)d_in[11];
    const float* b_concat = (const float*)d_in[12];
    const float* W_out    = (const float*)d_in[13];
    const float* W_critic = (const float*)d_in[14];
    const float* b_critic = (const float*)d_in[15];
    (void)in_sizes; (void)n_in; (void)out_size; (void)ws_size;

    const int M = BB * TT;                 // 32768

    float* out    = (float*)d_out;
    float* dact   = out;
    float* logits = out + M;
    float* values = out + M + (int64_t)M * OO;

    float* ws    = (float*)d_ws;
    float* gates = ws;                       // Ag0, 128 MB
    float* xbuf  = ws + 33554432;            // emb -> (zeroed) -> HX -> dec
    float* cat   = ws + 41943040;            // [M,512]: h1 | ctx
    float* keysR = ws + 58720256;
    float* keys  = keysR;
    uint4* Wpkh  = (uint4*)keysR;            // 1.5 MB; dead before keys
    u64*   AGU   = (u64*)(ws + 59500000);    // 8 MB stamped ring (dead-keys region)
    unsigned int* CCTR = (unsigned int*)(ws + 61600000);
    unsigned int* HX   = (unsigned int*)xbuf;
    float* scores = gates;
    float* qv     = gates;
    float* dec    = xbuf;

    // 1) embedding -> xbuf, + decoder_action
    hipLaunchKernelGGL(embed_kernel, dim3(M), dim3(256), 0, stream,
                       actions, emb_t, xbuf, dact);
    // 2) repack Whh0/Whh1/Wih1 to fp16 R10 layout
    hipLaunchKernelGGL(repack_w_kernel, dim3(384), dim3(256), 0, stream,
                       Whh, Wih, Wpkh);
    // 3) layer-0 input GEMM: gates = emb @ Wih0^T + bih0 + bhh0
    hipLaunchKernelGGL((mfma_gemm_kernel<true, 0>), dim3(8, 256, 1), dim3(256), 0, stream,
                       xbuf, Wih, gates, HT, HT, HT, GATES,
                       (int64_t)0, (int64_t)0, (int64_t)0, bih, bhh);
    // 4) zero h0-exchange buffer (emb consumed) + stamped ring + counters
    hipLaunchKernelGGL(hxzero_kernel, dim3(8192), dim3(256), 0, stream,
                       (uint4*)HX, AGU, CCTR);
    // 5) fused pipelined recurrence: L0 rec || L1 input || L1 rec
    hipLaunchKernelGGL(fused_rec_kernel, dim3(192), dim3(512), 0, stream,
                       gates, Wpkh, h0, c0, bih, bhh, cat, HX, AGU, CCTR);
    // 6) keys = enc @ W_attn^T + b_attn (MFMA fp16)
    hipLaunchKernelGGL((mfma_gemm_kernel<true, 0>), dim3(2, 256, 1), dim3(256), 0, stream,
                       enc, W_attn, keys, HT, HT, HT, HT,
                       (int64_t)0, (int64_t)0, (int64_t)0, b_attn, (const float*)nullptr);
    // 7) scores[b] = out[b] @ keys[b]^T  (MFMA fp16, fp32 accumulate)
    hipLaunchKernelGGL((mfma_gemm_kernel<true, 0>), dim3(4, 4, BB), dim3(256), 0, stream,
                       cat, keys, scores, HT, 2 * HT, HT, TT,
                       (int64_t)TT * 2 * HT, (int64_t)TT * HT, (int64_t)TT * TT,
                       (const float*)nullptr, (const float*)nullptr);
    // 8) softmax
    hipLaunchKernelGGL(softmax512_kernel, dim3(M / 4), dim3(256), 0, stream, scores);
    // 9) ctx[b] = P[b] @ enc[b] -> cat[:,256:]  (MFMA fp16)
    hipLaunchKernelGGL((mfma_gemm_kernel<false, 0>), dim3(2, 4, BB), dim3(256), 0, stream,
                       scores, enc, cat + HT, TT, TT, HT, 2 * HT,
                       (int64_t)TT * TT, (int64_t)TT * HT, (int64_t)TT * 2 * HT,
                       (const float*)nullptr, (const float*)nullptr);
    // 10) dec = tanh(cat @ W_concat^T + b_concat)
    hipLaunchKernelGGL((mfma_gemm_kernel<true, 1>), dim3(2, 256, 1), dim3(256), 0, stream,
                       cat, W_concat, dec, 2 * HT, 2 * HT, 2 * HT, HT,
                       (int64_t)0, (int64_t)0, (int64_t)0, b_concat, (const float*)nullptr);
    // 11) logits = dec @ W_out^T  (fp32 — output path)
    hipLaunchKernelGGL((gemm128_kernel<true, 0>), dim3(1, 256, 1), dim3(256), 0, stream,
                       dec, W_out, logits, HT, HT, HT, OO,
                       (int64_t)0, (int64_t)0, (int64_t)0,
                       (const float*)nullptr, (const float*)nullptr);
    // 12) qv = logits @ W_critic^T + b_critic  (fp32 — output path)
    hipLaunchKernelGGL((gemm128_kernel<true, 0>), dim3(1, 256, 1), dim3(256), 0, stream,
                       logits, W_critic, qv, OO, OO, OO, OO,
                       (int64_t)0, (int64_t)0, (int64_t)0, b_critic, (const float*)nullptr);
    // 13) values
    hipLaunchKernelGGL(values_kernel, dim3(M / 4), dim3(256), 0, stream,
                       qv, logits, values);
}